// Round 19
// baseline (200.788 us; speedup 1.0000x reference)
//
#include <hip/hip_runtime.h>
#include <hip/hip_bf16.h>

typedef unsigned short u16;
typedef unsigned int u32;
using short8 = __attribute__((ext_vector_type(8))) short;
using f32x4  = __attribute__((ext_vector_type(4))) float;
using f32x16 = __attribute__((ext_vector_type(16))) float;

#define MFMA16(a,b,c) __builtin_amdgcn_mfma_f32_16x16x32_bf16((a),(b),(c),0,0,0)
#define MFMA32(a,b,c) __builtin_amdgcn_mfma_f32_32x32x16_bf16((a),(b),(c),0,0,0)
#define EXP2F(x) __builtin_amdgcn_exp2f(x)

__device__ __forceinline__ float bf2f(u16 u){
  union { u32 i; float f; } v; v.i = ((u32)u)<<16; return v.f;
}
__device__ __forceinline__ u16 f2bf(float f){
  u32 x = __float_as_uint(f);
  x += 0x7fffu + ((x>>16)&1u);
  return (u16)(x>>16);
}
__device__ __forceinline__ u32 cvtpk(float lo, float hi){
  u32 r;
  asm("v_cvt_pk_bf16_f32 %0, %1, %2" : "=v"(r) : "v"(lo), "v"(hi));
  return r;
}
// SSA-safe cross-half exchange (lane i <-> lane i+32 halves merged)
__device__ __forceinline__ float cross_max(float v){
  u32 b = __float_as_uint(v);
  auto r = __builtin_amdgcn_permlane32_swap(b, b, false, false);
  return fmaxf(__uint_as_float(r[0]), __uint_as_float(r[1]));
}
__device__ __forceinline__ float cross_sum(float v){
  u32 b = __float_as_uint(v);
  auto r = __builtin_amdgcn_permlane32_swap(b, b, false, false);
  return __uint_as_float(r[0]) + __uint_as_float(r[1]);
}

typedef __attribute__((address_space(1))) const u32 GU32;
typedef __attribute__((address_space(3))) u32 LU32;
typedef __attribute__((address_space(3))) const u16 LDSU16C;
__device__ __forceinline__ void gload_lds16(const void* g, void* l){
  __builtin_amdgcn_global_load_lds((GU32*)g, (LU32*)l, 16, 0, 0);
}

template<int OFF>
__device__ __forceinline__ uint2 tr16(const u16* p){
  uint2 r;
  if constexpr (OFF == 0)
    asm volatile("ds_read_b64_tr_b16 %0, %1" : "=v"(r) : "v"((LDSU16C*)p));
  else
    asm volatile("ds_read_b64_tr_b16 %0, %1 offset:128" : "=v"(r) : "v"((LDSU16C*)p));
  return r;
}

// ---------------- fused fp32 -> bf16 converter ----------------
struct ConvArgs {
  const float4* in[14];
  uint2* out[14];
  int n4[14];
  int sb[15];
};
__global__ __launch_bounds__(256)
void conv_all(ConvArgs a)
{
  int bid = blockIdx.x;
  int s = 0;
  while (s < 13 && bid >= a.sb[s+1]) ++s;
  int i = (bid - a.sb[s])*256 + threadIdx.x;
  if (i >= a.n4[s]) return;
  float4 v = a.in[s][i];
  union { uint2 u; u16 h[4]; } o;
  o.h[0] = f2bf(v.x); o.h[1] = f2bf(v.y);
  o.h[2] = f2bf(v.z); o.h[3] = f2bf(v.w);
  a.out[s][i] = o.u;
}

// ---------------- LayerNorm (+ optional RoPE) ----------------
template<int DO_ROPE, int IN_F32>
__global__ __launch_bounds__(256)
void ln_kernel(const void* __restrict__ inv, const u16* __restrict__ lw,
               const u16* __restrict__ lb, const u16* __restrict__ ct,
               const u16* __restrict__ st, u16* __restrict__ xo,
               u16* __restrict__ xro)
{
  __shared__ float xs[4][512];
  int tid = threadIdx.x, wid = tid>>6, lane = tid&63;
  int m = blockIdx.x*4 + wid;
  int d0 = lane*8;
  float v[8], sum = 0.f, sq = 0.f;
  if (IN_F32){
    const float* in = (const float*)inv;
    float4 a = *(const float4*)(in + (size_t)m*512 + d0);
    float4 b = *(const float4*)(in + (size_t)m*512 + d0 + 4);
    v[0]=a.x; v[1]=a.y; v[2]=a.z; v[3]=a.w;
    v[4]=b.x; v[5]=b.y; v[6]=b.z; v[7]=b.w;
  } else {
    const u16* in = (const u16*)inv;
    union { uint4 q; u16 s[8]; } pk;
    pk.q = *(const uint4*)(in + (size_t)m*512 + d0);
#pragma unroll
    for (int j=0;j<8;j++) v[j] = bf2f(pk.s[j]);
  }
#pragma unroll
  for (int j=0;j<8;j++){ sum+=v[j]; sq+=v[j]*v[j]; }
#pragma unroll
  for (int o=1;o<64;o<<=1){ sum += __shfl_xor(sum,o); sq += __shfl_xor(sq,o); }
  float mean = sum*(1.f/512.f);
  float var  = sq*(1.f/512.f) - mean*mean;
  float rstd = rsqrtf(var + 1e-5f);
  float xn[8];
  union { uint4 q; u16 s[8]; } ou;
#pragma unroll
  for (int j=0;j<8;j++){
    int d = d0+j;
    xn[j] = (v[j]-mean)*rstd*bf2f(lw[d]) + bf2f(lb[d]);
    ou.s[j] = f2bf(xn[j]);
  }
  *(uint4*)(xo + (size_t)m*512 + d0) = ou.q;
  if (DO_ROPE){
#pragma unroll
    for (int j=0;j<8;j++) xs[wid][d0+j] = xn[j];
    __syncthreads();
    int si = m>>1;
    int hb = d0 & ~63;
#pragma unroll
    for (int j=0;j<8;j++){
      int d = d0+j, jh = d&63;
      float rh = (jh<32) ? -xs[wid][hb + 2*jh+1] : xs[wid][hb + 2*(jh-32)];
      float c  = bf2f(ct[si*64+jh]);
      float s2 = bf2f(st[si*64+jh]);
      ou.s[j] = f2bf(xn[j]*c + rh*s2);
    }
    *(uint4*)(xro + (size_t)m*512 + d0) = ou.q;
  }
}

// ---------------- GEMM: C[M,N] = A[M,K] * W[N,K]^T + bias (+epi) -------------
// BK=64, 32x32x16 MFMA, XOR-swizzled LDS, DOUBLE-BUFFERED (1 barrier/K-step).
#define EPI_NONE 0
#define EPI_GELU 1
#define EPI_RES  2

// SELA: resv doubles as second A (bn>=8 => V cols of fused QKV). BM: 128 or 64.
template<int EPI, int RES_F32, int OUT_F32, int QSCL, int SELA, int BM>
__global__ __launch_bounds__(256)
void gemm_bt(const u16* __restrict__ A, const u16* __restrict__ W,
             const u16* __restrict__ bias, const void* __restrict__ resv,
             void* __restrict__ Cv, int M, int N, int K)
{
  constexpr int IF = BM/32;          // A-stage issues per wave
  constexpr int RF = BM/64;          // 32-row frags per wave
  __shared__ u16 As[2][BM*64];
  __shared__ u16 Bs[2][128*64];
  int tid = threadIdx.x, wid = tid>>6, lane = tid&63;
  int l31 = lane & 31, hi = lane >> 5;
  int nbn = N >> 7;
  int bm = blockIdx.x / nbn, bn = blockIdx.x % nbn;
  int wr = wid >> 1, wc = wid & 1;
  f32x16 acc[RF][2];
#pragma unroll
  for (int i=0;i<RF;i++)
#pragma unroll
    for (int j=0;j<2;j++)
#pragma unroll
      for (int t=0;t<16;t++) acc[i][j][t] = 0.f;

  const u16* Ap = (SELA && bn >= 8) ? (const u16*)resv : A;
  const u16* Abase = Ap + (size_t)(bm*BM)*K;
  const u16* Wbase = W + (size_t)(bn*128)*K;
  int srow = lane>>3;                          // 0..7 (row within 8-row stripe)
  int schk = ((lane&7) ^ srow) << 3;           // pre-swizzled source chunk (u16)

#define GSTAGE(KB, BUF)                                                          \
  {                                                                              \
    _Pragma("unroll")                                                            \
    for (int i=0;i<IF;i++){                                                      \
      int row = wid*(8*IF) + i*8 + srow;                                         \
      gload_lds16(Abase + (size_t)row*K + (KB) + schk,                           \
                  &As[BUF][(wid*(8*IF) + i*8)*64]);                              \
    }                                                                            \
    _Pragma("unroll")                                                            \
    for (int i=0;i<4;i++){                                                       \
      int row = wid*32 + i*8 + srow;                                             \
      gload_lds16(Wbase + (size_t)row*K + (KB) + schk,                           \
                  &Bs[BUF][(wid*32 + i*8)*64]);                                  \
    }                                                                            \
  }

  GSTAGE(0, 0);
  int cur = 0;

  for (int kb = 0; kb < K; kb += 64){
    __syncthreads();                 // buf[cur] DMA landed; all reads of buf[cur^1] done
    if (kb + 64 < K) GSTAGE(kb + 64, cur^1);
#pragma unroll
    for (int ks=0; ks<4; ++ks){
      short8 af[RF], bf8[2];
#pragma unroll
      for (int i=0;i<RF;i++){
        int row = wr*(BM/2) + i*32 + l31;
        af[i] = *(const short8*)&As[cur][row*64 + (((2*ks + hi) ^ (row&7))<<3)];
      }
#pragma unroll
      for (int j=0;j<2;j++){
        int colr = wc*64 + j*32 + l31;
        bf8[j] = *(const short8*)&Bs[cur][colr*64 + (((2*ks + hi) ^ (colr&7))<<3)];
      }
#pragma unroll
      for (int i=0;i<RF;i++)
#pragma unroll
        for (int j=0;j<2;j++)
          acc[i][j] = MFMA32(af[i], bf8[j], acc[i][j]);
    }
    cur ^= 1;
  }
#undef GSTAGE
  // epilogue: C row = (t&3)+8*(t>>2)+4*hi (A-operand), col = l31 (B-operand)
#pragma unroll
  for (int i=0;i<RF;i++){
#pragma unroll
    for (int j=0;j<2;j++){
      int col = bn*128 + wc*64 + j*32 + l31;
      float bv = bf2f(bias[col]);
#pragma unroll
      for (int t=0;t<16;t++){
        int row = bm*BM + wr*(BM/2) + i*32 + (t&3) + 8*(t>>2) + 4*hi;
        size_t idx = (size_t)row*N + col;
        float x = acc[i][j][t] + bv;
        if (EPI == EPI_GELU) x = 0.5f*x*(1.f + erff(x*0.70710678118f));
        if (EPI == EPI_RES){
          if (RES_F32) x += ((const float*)resv)[idx];
          else         x += bf2f(((const u16*)resv)[idx]);
        }
        if (QSCL && col < 512) x *= 0.18033688011f;  // 0.125*log2(e): softmax exp2 domain
        if (OUT_F32) ((float*)Cv)[idx] = x;
        else         ((u16*)Cv)[idx]   = f2bf(x);
      }
    }
  }
}

// ---------------- Causal flash attention: split-kv, KVBLK=64, 32KB LDS ------
// QKV layout [4096][2][1536]: Q cols 0..511, K 512..1023, V 1024..1535.
// grid 896: bid<768: split chunks (qt>=8, 2 kv-halves, heavy first) -> partials
//           bid>=768: direct rows (qt=7..0) -> O
// launch_bounds(256,3): 170-reg budget -> full tr16 hoist fits (no spill).
__global__ __launch_bounds__(256, 3)
void attn_kernel(const u16* __restrict__ QKV, u16* __restrict__ Opart,
                 float* __restrict__ ml, u16* __restrict__ O)
{
  __shared__ u16 Ks[2][64*64];      // 8KB each, swizzled: LDS(r,cb)=K(r, cb^((r&7)<<4))
  __shared__ u16 Vp[2][4*1024];     // 8KB each, 4 panels [64 kv][16 d]
  int tid = threadIdx.x, wid = tid>>6, lane = tid&63;
  int l15 = lane&15, q5 = lane&31, hi = lane>>5;
  int bid = blockIdx.x;
  int qt, kt0, kt1, cid = bid;
  bool split = (bid < 768);
  if (split){
    int idx = bid >> 4;              // 0..47 heavy-first
    qt = 31 - (idx >> 1);            // 31..8
    int half = idx & 1;
    int nk = 2*qt + 2, h0 = nk >> 1; // qt+1
    kt0 = half ? h0 : 0; kt1 = half ? nk : h0;
  } else {
    qt = 7 - ((bid - 768) >> 4);
    kt0 = 0; kt1 = 2*qt + 2;
  }
  int bh = bid & 15;
  int b = bh>>3, h = bh&7;
  size_t qkvb = (size_t)b*1536 + h*64;
  size_t vbh  = (size_t)b*512  + h*64;

  int qrow = qt*128 + wid*32 + q5;        // this lane's q (column of S^T/O^T)
  short8 aQ[4];
#pragma unroll
  for (int kc=0; kc<4; ++kc)
    aQ[kc] = *(const short8*)(QKV + (size_t)qrow*3072 + qkvb + 16*kc + 8*hi);

  f32x16 oacc[2];
#pragma unroll
  for (int dblk=0; dblk<2; ++dblk)
#pragma unroll
    for (int r=0;r<16;r++) oacc[dblk][r] = 0.f;
  float mrun = -3e38f, lrun = 0.f;

#define STAGE(KT, BUF)                                                              \
  {                                                                                 \
    _Pragma("unroll")                                                               \
    for (int i=0;i<2;++i){                                                          \
      gload_lds16(QKV + (size_t)((KT)*64 + wid*16 + i*8 + (lane>>3))*3072 + qkvb    \
                      + 512 + (((lane&7)^(lane>>3))<<3),                            \
                  &Ks[BUF][(wid*16 + i*8)*64]);                                     \
      int j = wid*2 + i, p = j>>1, rh = (j&1)*32;                                   \
      gload_lds16(QKV + (size_t)((KT)*64 + rh + (lane>>1))*3072 + qkvb              \
                      + 1024 + p*16 + ((lane&1)<<3),                                \
                  &Vp[BUF][p*1024 + rh*16]);                                        \
    }                                                                               \
  }

  STAGE(kt0, 0);
  int cur = 0;

  for (int kt=kt0; kt<kt1; ++kt){
    __syncthreads();                 // drains DMA -> buf[cur] ready
    if (kt+1 < kt1) STAGE(kt+1, cur^1);

    // S^T = K @ Q^T : col=q5, 2 sub-accs of 32 kv rows
    f32x16 sacc[2];
#pragma unroll
    for (int s=0;s<2;s++)
#pragma unroll
      for (int r=0;r<16;r++) sacc[s][r] = 0.f;
    __builtin_amdgcn_s_setprio(1);
#pragma unroll
    for (int kc=0; kc<4; ++kc)
#pragma unroll
      for (int s=0; s<2; ++s){
        int cb = (32*kc + 16*hi) ^ ((q5&7)<<4);   // bytes, XOR read swizzle
        short8 aK = *(const short8*)&Ks[cur][(32*s + q5)*64 + (cb>>1)];
        sacc[s] = MFMA32(aK, aQ[kc], sacc[s]);
      }
    __builtin_amdgcn_s_setprio(0);

    // issue ALL V transpose-reads now; LDS latency hides under softmax (32 VGPR)
    uint2 av[4][2][2];
#pragma unroll
    for (int kc=0; kc<4; ++kc)
#pragma unroll
      for (int dblk=0; dblk<2; ++dblk){
        const u16* base = &Vp[cur][(((lane>>4)&1) + 2*dblk)*1024 + (16*kc + 8*hi)*16 + l15*4];
        av[kc][dblk][0] = tr16<0>(base);
        av[kc][dblk][1] = tr16<128>(base);
      }

    // lane-local online softmax (values pre-scaled into exp2 domain)
    bool diag = (kt >= 2*qt);
    float pm[4] = {-3e38f,-3e38f,-3e38f,-3e38f};
#pragma unroll
    for (int s=0;s<2;++s)
#pragma unroll
      for (int r=0;r<16;++r){
        float x = sacc[s][r];
        if (diag){
          int kv = kt*64 + 32*s + (r&3) + 8*(r>>2) + 4*hi;
          if (kv > qrow) x = -3e38f;
          sacc[s][r] = x;
        }
        pm[r&3] = fmaxf(pm[r&3], x);
      }
    float pmax = fmaxf(fmaxf(pm[0],pm[1]), fmaxf(pm[2],pm[3]));
    pmax = cross_max(pmax);
    // T13 defer-max: only rescale when max grew by > 8 (P bounded by 2^8)
    if (!__all(pmax <= mrun + 8.f)){
      float mn = fmaxf(mrun, pmax);
      float alpha = EXP2F(mrun - mn);
      mrun = mn;
      lrun *= alpha;
#pragma unroll
      for (int dblk=0; dblk<2; ++dblk)
#pragma unroll
        for (int r=0;r<16;++r) oacc[dblk][r] *= alpha;
    }
    float ps = 0.f;
    u32 Wp[2][4][2];
#pragma unroll
    for (int s=0;s<2;++s)
#pragma unroll
      for (int p=0;p<4;++p){
        float e0 = EXP2F(sacc[s][4*p+0]-mrun);
        float e1 = EXP2F(sacc[s][4*p+1]-mrun);
        float e2 = EXP2F(sacc[s][4*p+2]-mrun);
        float e3 = EXP2F(sacc[s][4*p+3]-mrun);
        ps += (e0+e1)+(e2+e3);
        Wp[s][p][0] = cvtpk(e0,e1);
        Wp[s][p][1] = cvtpk(e2,e3);
      }
    ps = cross_sum(ps);
    lrun += ps;

    // single wait for all tr-reads (issued pre-softmax), then pure-reg PV
    asm volatile("s_waitcnt lgkmcnt(0)");
    __builtin_amdgcn_sched_barrier(0);
    __builtin_amdgcn_s_setprio(1);
#pragma unroll
    for (int kc=0; kc<4; ++kc){
      int s = kc>>1, pA = (2*kc)&3, pB = (2*kc+1)&3;
      auto r0 = __builtin_amdgcn_permlane32_swap(Wp[s][pA][0], Wp[s][pB][0], false, false);
      auto r1 = __builtin_amdgcn_permlane32_swap(Wp[s][pA][1], Wp[s][pB][1], false, false);
      union { u32 w[4]; short8 s8; } bp;
      bp.w[0]=r0[0]; bp.w[1]=r1[0]; bp.w[2]=r0[1]; bp.w[3]=r1[1];
      union { uint2 u2[2]; short8 s8; } a0, a1;
      a0.u2[0]=av[kc][0][0]; a0.u2[1]=av[kc][0][1];
      a1.u2[0]=av[kc][1][0]; a1.u2[1]=av[kc][1][1];
      oacc[0] = MFMA32(a0.s8, bp.s8, oacc[0]);
      oacc[1] = MFMA32(a1.s8, bp.s8, oacc[1]);
    }
    __builtin_amdgcn_s_setprio(0);
    cur ^= 1;
  }

  if (split){
    // unnormalized partial O^T + (m,l) per q
    u16* po = Opart + (size_t)cid*8192 + (wid*32 + q5)*64;
#pragma unroll
    for (int dblk=0; dblk<2; ++dblk)
#pragma unroll
      for (int p=0;p<4;++p){
        int d0 = 32*dblk + 8*p + 4*hi;
        union { uint2 u; u16 hh[4]; } o;
#pragma unroll
        for (int r=0;r<4;++r) o.hh[r] = f2bf(oacc[dblk][4*p+r]);
        *(uint2*)(po + d0) = o.u;
      }
    if (lane < 32){
      ml[((size_t)cid*128 + wid*32 + q5)*2 + 0] = mrun;
      ml[((size_t)cid*128 + wid*32 + q5)*2 + 1] = lrun;
    }
  } else {
    float rcp = 1.f / lrun;
#pragma unroll
    for (int dblk=0; dblk<2; ++dblk)
#pragma unroll
      for (int p=0;p<4;++p){
        int d0 = 32*dblk + 8*p + 4*hi;
        union { uint2 u; u16 hh[4]; } o;
#pragma unroll
        for (int r=0;r<4;++r) o.hh[r] = f2bf(oacc[dblk][4*p+r] * rcp);
        *(uint2*)(O + (size_t)qrow*1024 + vbh + d0) = o.u;
      }
  }
#undef STAGE
}

// ---------------- combine: merge 2 kv-chunks for qt>=8 -----------------------
__global__ __launch_bounds__(128)
void attn_combine(const u16* __restrict__ Opart, const float* __restrict__ ml,
                  u16* __restrict__ O)
{
  int cb = blockIdx.x >> 4;                  // 0..23
  int qt = 31 - cb;                          // 31..8
  int bh = blockIdx.x & 15;
  int b = bh>>3, h = bh&7;
  int q = threadIdx.x;                       // 0..127
  int cid0 = (cb*2)*16 + bh, cid1 = cid0 + 16;
  float m0 = ml[((size_t)cid0*128 + q)*2], l0 = ml[((size_t)cid0*128 + q)*2 + 1];
  float m1 = ml[((size_t)cid1*128 + q)*2], l1 = ml[((size_t)cid1*128 + q)*2 + 1];
  float mx = fmaxf(m0, m1);
  float w0 = EXP2F(m0 - mx), w1 = EXP2F(m1 - mx);
  float rcp = 1.f / (w0*l0 + w1*l1);
  w0 *= rcp; w1 *= rcp;
  const u16* p0 = Opart + ((size_t)cid0*128 + q)*64;
  const u16* p1 = Opart + ((size_t)cid1*128 + q)*64;
  u16* o = O + (size_t)(qt*128 + q)*1024 + b*512 + h*64;
#pragma unroll
  for (int d0=0; d0<64; d0+=8){
    union { uint4 v; u16 s[8]; } a, c, r;
    a.v = *(const uint4*)(p0 + d0);
    c.v = *(const uint4*)(p1 + d0);
#pragma unroll
    for (int j=0;j<8;j++) r.s[j] = f2bf(w0*bf2f(a.s[j]) + w1*bf2f(c.s[j]));
    *(uint4*)(o + d0) = r.v;
  }
}

// ---------------- launch ----------------
extern "C" void kernel_launch(void* const* d_in, const int* in_sizes, int n_in,
                              void* d_out, int out_size, void* d_ws, size_t ws_size,
                              hipStream_t stream)
{
  float* out = (float*)d_out;
  const float* src_f = (const float*)d_in[0];
  char* ws = (char*)d_ws;
  const size_t MB = 1024ull*1024ull;
  u16* xbuf = (u16*)(ws);            // [0,8)   x ; later attn-out
  u16* xr   = (u16*)(ws +  8*MB);    // [8,16)  RoPE(x) ; later src2
  u16* qkv  = (u16*)(ws + 16*MB);    // [16,40) fused Q|K|V [8192][1536]
  u16* y2   = (u16*)(ws + 16*MB);    // [16,24) LN2 out (qkv dead by then)
  u16* hb   = (u16*)(ws + 24*MB);    // [24,56) FFN hidden
  u16* opart= (u16*)(ws + 40*MB);    // [40,52) attn partials (dead before FFN1)
  float* mlb= (float*)(ws + 52*MB);  // [52,52.75) m/l partials
  u16* arena= (u16*)(ws + 56*MB);    // ~7.33MB converted bf16 weights
  u16* attn = xbuf;
  u16* src2 = xr;

  ConvArgs ca;
  u16* cv[15]; cv[0] = nullptr;
  {
    size_t off = 0; int blk = 0;
    for (int i=1;i<15;i++){
      cv[i] = arena + off;
      int n = in_sizes[i];
      ca.in[i-1]  = (const float4*)d_in[i];
      ca.out[i-1] = (uint2*)cv[i];
      ca.n4[i-1]  = n >> 2;
      ca.sb[i-1]  = blk;
      blk += ((n>>2) + 255) / 256;
      off += (size_t)n;
    }
    ca.sb[14] = blk;
    conv_all<<<blk, 256, 0, stream>>>(ca);
  }
  const u16* rcos = cv[1];
  const u16* rsin = cv[2];
  const u16* inw  = cv[3];
  const u16* inb  = cv[4];
  const u16* outw = cv[5];
  const u16* outb = cv[6];
  const u16* w1   = cv[7];
  const u16* b1   = cv[8];
  const u16* w2   = cv[9];
  const u16* b2   = cv[10];
  const u16* ln1w = cv[11];
  const u16* ln1b = cv[12];
  const u16* ln2w = cv[13];
  const u16* ln2b = cv[14];

  ln_kernel<1,1><<<2048, 256, 0, stream>>>(src_f, ln1w, ln1b, rcos, rsin, xbuf, xr);

  // fused Q|K|V projection: A = xr for cols<1024 (bn<8), xbuf for V cols (bn>=8)
  gemm_bt<EPI_NONE,0,0,1,1,128><<<768, 256, 0, stream>>>(xr, inw, inb, xbuf, qkv, 8192, 1536, 512);

  attn_kernel<<<896, 256, 0, stream>>>(qkv, opart, mlb, attn);
  attn_combine<<<384, 128, 0, stream>>>(opart, mlb, attn);

  gemm_bt<EPI_RES,1,0,0,0,64><<<512, 256, 0, stream>>>(attn, outw, outb, src_f, src2, 8192, 512, 512);

  ln_kernel<0,0><<<2048, 256, 0, stream>>>(src2, ln2w, ln2b, nullptr, nullptr, y2, nullptr);

  gemm_bt<EPI_GELU,0,0,0,0,128><<<1024, 256, 0, stream>>>(y2, w1, b1, nullptr, hb, 8192, 2048, 512);
  gemm_bt<EPI_RES,0,1,0,0,64><<<512, 256, 0, stream>>>(hb, w2, b2, src2, out, 8192, 512, 2048);
}

// Round 20
// 195.147 us; speedup vs baseline: 1.0289x; 1.0289x over previous
//
#include <hip/hip_runtime.h>
#include <hip/hip_bf16.h>

typedef unsigned short u16;
typedef unsigned int u32;
using short8 = __attribute__((ext_vector_type(8))) short;
using f32x4  = __attribute__((ext_vector_type(4))) float;
using f32x16 = __attribute__((ext_vector_type(16))) float;

#define MFMA16(a,b,c) __builtin_amdgcn_mfma_f32_16x16x32_bf16((a),(b),(c),0,0,0)
#define MFMA32(a,b,c) __builtin_amdgcn_mfma_f32_32x32x16_bf16((a),(b),(c),0,0,0)
#define EXP2F(x) __builtin_amdgcn_exp2f(x)

__device__ __forceinline__ float bf2f(u16 u){
  union { u32 i; float f; } v; v.i = ((u32)u)<<16; return v.f;
}
__device__ __forceinline__ u16 f2bf(float f){
  u32 x = __float_as_uint(f);
  x += 0x7fffu + ((x>>16)&1u);
  return (u16)(x>>16);
}
__device__ __forceinline__ u32 cvtpk(float lo, float hi){
  u32 r;
  asm("v_cvt_pk_bf16_f32 %0, %1, %2" : "=v"(r) : "v"(lo), "v"(hi));
  return r;
}
// SSA-safe cross-half exchange (lane i <-> lane i+32 halves merged)
__device__ __forceinline__ float cross_max(float v){
  u32 b = __float_as_uint(v);
  auto r = __builtin_amdgcn_permlane32_swap(b, b, false, false);
  return fmaxf(__uint_as_float(r[0]), __uint_as_float(r[1]));
}
__device__ __forceinline__ float cross_sum(float v){
  u32 b = __float_as_uint(v);
  auto r = __builtin_amdgcn_permlane32_swap(b, b, false, false);
  return __uint_as_float(r[0]) + __uint_as_float(r[1]);
}

typedef __attribute__((address_space(1))) const u32 GU32;
typedef __attribute__((address_space(3))) u32 LU32;
typedef __attribute__((address_space(3))) const u16 LDSU16C;
__device__ __forceinline__ void gload_lds16(const void* g, void* l){
  __builtin_amdgcn_global_load_lds((GU32*)g, (LU32*)l, 16, 0, 0);
}

template<int OFF>
__device__ __forceinline__ uint2 tr16(const u16* p){
  uint2 r;
  if constexpr (OFF == 0)
    asm volatile("ds_read_b64_tr_b16 %0, %1" : "=v"(r) : "v"((LDSU16C*)p));
  else
    asm volatile("ds_read_b64_tr_b16 %0, %1 offset:128" : "=v"(r) : "v"((LDSU16C*)p));
  return r;
}

// ---------------- fused fp32 -> bf16 converter ----------------
struct ConvArgs {
  const float4* in[14];
  uint2* out[14];
  int n4[14];
  int sb[15];
};
__global__ __launch_bounds__(256)
void conv_all(ConvArgs a)
{
  int bid = blockIdx.x;
  int s = 0;
  while (s < 13 && bid >= a.sb[s+1]) ++s;
  int i = (bid - a.sb[s])*256 + threadIdx.x;
  if (i >= a.n4[s]) return;
  float4 v = a.in[s][i];
  union { uint2 u; u16 h[4]; } o;
  o.h[0] = f2bf(v.x); o.h[1] = f2bf(v.y);
  o.h[2] = f2bf(v.z); o.h[3] = f2bf(v.w);
  a.out[s][i] = o.u;
}

// ---------------- LayerNorm (+ optional RoPE) ----------------
template<int DO_ROPE, int IN_F32>
__global__ __launch_bounds__(256)
void ln_kernel(const void* __restrict__ inv, const u16* __restrict__ lw,
               const u16* __restrict__ lb, const u16* __restrict__ ct,
               const u16* __restrict__ st, u16* __restrict__ xo,
               u16* __restrict__ xro)
{
  __shared__ float xs[4][512];
  int tid = threadIdx.x, wid = tid>>6, lane = tid&63;
  int m = blockIdx.x*4 + wid;
  int d0 = lane*8;
  float v[8], sum = 0.f, sq = 0.f;
  if (IN_F32){
    const float* in = (const float*)inv;
    float4 a = *(const float4*)(in + (size_t)m*512 + d0);
    float4 b = *(const float4*)(in + (size_t)m*512 + d0 + 4);
    v[0]=a.x; v[1]=a.y; v[2]=a.z; v[3]=a.w;
    v[4]=b.x; v[5]=b.y; v[6]=b.z; v[7]=b.w;
  } else {
    const u16* in = (const u16*)inv;
    union { uint4 q; u16 s[8]; } pk;
    pk.q = *(const uint4*)(in + (size_t)m*512 + d0);
#pragma unroll
    for (int j=0;j<8;j++) v[j] = bf2f(pk.s[j]);
  }
#pragma unroll
  for (int j=0;j<8;j++){ sum+=v[j]; sq+=v[j]*v[j]; }
#pragma unroll
  for (int o=1;o<64;o<<=1){ sum += __shfl_xor(sum,o); sq += __shfl_xor(sq,o); }
  float mean = sum*(1.f/512.f);
  float var  = sq*(1.f/512.f) - mean*mean;
  float rstd = rsqrtf(var + 1e-5f);
  float xn[8];
  union { uint4 q; u16 s[8]; } ou;
#pragma unroll
  for (int j=0;j<8;j++){
    int d = d0+j;
    xn[j] = (v[j]-mean)*rstd*bf2f(lw[d]) + bf2f(lb[d]);
    ou.s[j] = f2bf(xn[j]);
  }
  *(uint4*)(xo + (size_t)m*512 + d0) = ou.q;
  if (DO_ROPE){
#pragma unroll
    for (int j=0;j<8;j++) xs[wid][d0+j] = xn[j];
    __syncthreads();
    int si = m>>1;
    int hb = d0 & ~63;
#pragma unroll
    for (int j=0;j<8;j++){
      int d = d0+j, jh = d&63;
      float rh = (jh<32) ? -xs[wid][hb + 2*jh+1] : xs[wid][hb + 2*(jh-32)];
      float c  = bf2f(ct[si*64+jh]);
      float s2 = bf2f(st[si*64+jh]);
      ou.s[j] = f2bf(xn[j]*c + rh*s2);
    }
    *(uint4*)(xro + (size_t)m*512 + d0) = ou.q;
  }
}

// ---------------- GEMM: C[M,N] = A[M,K] * W[N,K]^T + bias (+epi) -------------
// BK=64, 32x32x16 MFMA, XOR-swizzled LDS (pre-swizzled source; chunk^=(row&7)).
// Single-buffered: multi-block TLP already hides staging (r19 showed dbuf
// costs occupancy for zero pipeline gain).
#define EPI_NONE 0
#define EPI_GELU 1
#define EPI_RES  2

// SELA: resv doubles as second A (bn>=8 => V cols of fused QKV). BM: 128 or 64.
template<int EPI, int RES_F32, int OUT_F32, int QSCL, int SELA, int BM>
__global__ __launch_bounds__(256)
void gemm_bt(const u16* __restrict__ A, const u16* __restrict__ W,
             const u16* __restrict__ bias, const void* __restrict__ resv,
             void* __restrict__ Cv, int M, int N, int K)
{
  constexpr int IF = BM/32;          // A-stage issues per wave
  constexpr int RF = BM/64;          // 32-row frags per wave
  __shared__ u16 As[BM*64];
  __shared__ u16 Bs[128*64];
  int tid = threadIdx.x, wid = tid>>6, lane = tid&63;
  int l31 = lane & 31, hi = lane >> 5;
  int nbn = N >> 7;
  int bm = blockIdx.x / nbn, bn = blockIdx.x % nbn;
  int wr = wid >> 1, wc = wid & 1;
  f32x16 acc[RF][2];
#pragma unroll
  for (int i=0;i<RF;i++)
#pragma unroll
    for (int j=0;j<2;j++)
#pragma unroll
      for (int t=0;t<16;t++) acc[i][j][t] = 0.f;

  const u16* Ap = (SELA && bn >= 8) ? (const u16*)resv : A;
  const u16* Abase = Ap + (size_t)(bm*BM)*K;
  const u16* Wbase = W + (size_t)(bn*128)*K;
  int srow = lane>>3;                          // 0..7 (row within 8-row stripe)
  int schk = ((lane&7) ^ srow) << 3;           // pre-swizzled source chunk (u16)

  for (int kb = 0; kb < K; kb += 64){
    // stage: 8 rows per issue, linear dest, swizzled source
#pragma unroll
    for (int i=0;i<IF;i++){
      int row = wid*(8*IF) + i*8 + srow;
      gload_lds16(Abase + (size_t)row*K + kb + schk, &As[(wid*(8*IF) + i*8)*64]);
    }
#pragma unroll
    for (int i=0;i<4;i++){
      int row = wid*32 + i*8 + srow;
      gload_lds16(Wbase + (size_t)row*K + kb + schk, &Bs[(wid*32 + i*8)*64]);
    }
    __syncthreads();
#pragma unroll
    for (int ks=0; ks<4; ++ks){
      short8 af[RF], bf8[2];
#pragma unroll
      for (int i=0;i<RF;i++){
        int row = wr*(BM/2) + i*32 + l31;
        af[i] = *(const short8*)&As[row*64 + (((2*ks + hi) ^ (row&7))<<3)];
      }
#pragma unroll
      for (int j=0;j<2;j++){
        int colr = wc*64 + j*32 + l31;
        bf8[j] = *(const short8*)&Bs[colr*64 + (((2*ks + hi) ^ (colr&7))<<3)];
      }
#pragma unroll
      for (int i=0;i<RF;i++)
#pragma unroll
        for (int j=0;j<2;j++)
          acc[i][j] = MFMA32(af[i], bf8[j], acc[i][j]);
    }
    __syncthreads();
  }
  // epilogue: C row = (t&3)+8*(t>>2)+4*hi (A-operand), col = l31 (B-operand)
#pragma unroll
  for (int i=0;i<RF;i++){
#pragma unroll
    for (int j=0;j<2;j++){
      int col = bn*128 + wc*64 + j*32 + l31;
      float bv = bf2f(bias[col]);
#pragma unroll
      for (int t=0;t<16;t++){
        int row = bm*BM + wr*(BM/2) + i*32 + (t&3) + 8*(t>>2) + 4*hi;
        size_t idx = (size_t)row*N + col;
        float x = acc[i][j][t] + bv;
        if (EPI == EPI_GELU) x = 0.5f*x*(1.f + erff(x*0.70710678118f));
        if (EPI == EPI_RES){
          if (RES_F32) x += ((const float*)resv)[idx];
          else         x += bf2f(((const u16*)resv)[idx]);
        }
        if (QSCL && col < 512) x *= 0.18033688011f;  // 0.125*log2(e): softmax exp2 domain
        if (OUT_F32) ((float*)Cv)[idx] = x;
        else         ((u16*)Cv)[idx]   = f2bf(x);
      }
    }
  }
}

// ---------------- Causal flash attention: split-kv, KVBLK=64, 32KB LDS ------
// QKV layout [4096][2][1536]: Q cols 0..511, K 512..1023, V 1024..1535.
// grid 896: bid<768: split chunks (qt>=8, 2 kv-halves, heavy first) -> partials
//           bid>=768: direct rows (qt=7..0) -> O
// launch_bounds(256,3): 170-reg budget -> full tr16 hoist fits (no spill).
__global__ __launch_bounds__(256, 3)
void attn_kernel(const u16* __restrict__ QKV, u16* __restrict__ Opart,
                 float* __restrict__ ml, u16* __restrict__ O)
{
  __shared__ u16 Ks[2][64*64];      // 8KB each, swizzled: LDS(r,cb)=K(r, cb^((r&7)<<4))
  __shared__ u16 Vp[2][4*1024];     // 8KB each, 4 panels [64 kv][16 d]
  int tid = threadIdx.x, wid = tid>>6, lane = tid&63;
  int l15 = lane&15, q5 = lane&31, hi = lane>>5;
  int bid = blockIdx.x;
  int qt, kt0, kt1, cid = bid;
  bool split = (bid < 768);
  if (split){
    int idx = bid >> 4;              // 0..47 heavy-first
    qt = 31 - (idx >> 1);            // 31..8
    int half = idx & 1;
    int nk = 2*qt + 2, h0 = nk >> 1; // qt+1
    kt0 = half ? h0 : 0; kt1 = half ? nk : h0;
  } else {
    qt = 7 - ((bid - 768) >> 4);
    kt0 = 0; kt1 = 2*qt + 2;
  }
  int bh = bid & 15;
  int b = bh>>3, h = bh&7;
  size_t qkvb = (size_t)b*1536 + h*64;
  size_t vbh  = (size_t)b*512  + h*64;

  int qrow = qt*128 + wid*32 + q5;        // this lane's q (column of S^T/O^T)
  short8 aQ[4];
#pragma unroll
  for (int kc=0; kc<4; ++kc)
    aQ[kc] = *(const short8*)(QKV + (size_t)qrow*3072 + qkvb + 16*kc + 8*hi);

  f32x16 oacc[2];
#pragma unroll
  for (int dblk=0; dblk<2; ++dblk)
#pragma unroll
    for (int r=0;r<16;r++) oacc[dblk][r] = 0.f;
  float mrun = -3e38f, lrun = 0.f;

#define STAGE(KT, BUF)                                                              \
  {                                                                                 \
    _Pragma("unroll")                                                               \
    for (int i=0;i<2;++i){                                                          \
      gload_lds16(QKV + (size_t)((KT)*64 + wid*16 + i*8 + (lane>>3))*3072 + qkvb    \
                      + 512 + (((lane&7)^(lane>>3))<<3),                            \
                  &Ks[BUF][(wid*16 + i*8)*64]);                                     \
      int j = wid*2 + i, p = j>>1, rh = (j&1)*32;                                   \
      gload_lds16(QKV + (size_t)((KT)*64 + rh + (lane>>1))*3072 + qkvb              \
                      + 1024 + p*16 + ((lane&1)<<3),                                \
                  &Vp[BUF][p*1024 + rh*16]);                                        \
    }                                                                               \
  }

  STAGE(kt0, 0);
  int cur = 0;

  for (int kt=kt0; kt<kt1; ++kt){
    __syncthreads();                 // drains DMA -> buf[cur] ready
    if (kt+1 < kt1) STAGE(kt+1, cur^1);

    // S^T = K @ Q^T : col=q5, 2 sub-accs of 32 kv rows
    f32x16 sacc[2];
#pragma unroll
    for (int s=0;s<2;s++)
#pragma unroll
      for (int r=0;r<16;r++) sacc[s][r] = 0.f;
    __builtin_amdgcn_s_setprio(1);
#pragma unroll
    for (int kc=0; kc<4; ++kc)
#pragma unroll
      for (int s=0; s<2; ++s){
        int cb = (32*kc + 16*hi) ^ ((q5&7)<<4);   // bytes, XOR read swizzle
        short8 aK = *(const short8*)&Ks[cur][(32*s + q5)*64 + (cb>>1)];
        sacc[s] = MFMA32(aK, aQ[kc], sacc[s]);
      }
    __builtin_amdgcn_s_setprio(0);

    // issue ALL V transpose-reads now; LDS latency hides under softmax (32 VGPR)
    uint2 av[4][2][2];
#pragma unroll
    for (int kc=0; kc<4; ++kc)
#pragma unroll
      for (int dblk=0; dblk<2; ++dblk){
        const u16* base = &Vp[cur][(((lane>>4)&1) + 2*dblk)*1024 + (16*kc + 8*hi)*16 + l15*4];
        av[kc][dblk][0] = tr16<0>(base);
        av[kc][dblk][1] = tr16<128>(base);
      }

    // lane-local online softmax (values pre-scaled into exp2 domain)
    bool diag = (kt >= 2*qt);
    float pm[4] = {-3e38f,-3e38f,-3e38f,-3e38f};
#pragma unroll
    for (int s=0;s<2;++s)
#pragma unroll
      for (int r=0;r<16;++r){
        float x = sacc[s][r];
        if (diag){
          int kv = kt*64 + 32*s + (r&3) + 8*(r>>2) + 4*hi;
          if (kv > qrow) x = -3e38f;
          sacc[s][r] = x;
        }
        pm[r&3] = fmaxf(pm[r&3], x);
      }
    float pmax = fmaxf(fmaxf(pm[0],pm[1]), fmaxf(pm[2],pm[3]));
    pmax = cross_max(pmax);
    // T13 defer-max: only rescale when max grew by > 8 (P bounded by 2^8)
    if (!__all(pmax <= mrun + 8.f)){
      float mn = fmaxf(mrun, pmax);
      float alpha = EXP2F(mrun - mn);
      mrun = mn;
      lrun *= alpha;
#pragma unroll
      for (int dblk=0; dblk<2; ++dblk)
#pragma unroll
        for (int r=0;r<16;++r) oacc[dblk][r] *= alpha;
    }
    float ps = 0.f;
    u32 Wp[2][4][2];
#pragma unroll
    for (int s=0;s<2;++s)
#pragma unroll
      for (int p=0;p<4;++p){
        float e0 = EXP2F(sacc[s][4*p+0]-mrun);
        float e1 = EXP2F(sacc[s][4*p+1]-mrun);
        float e2 = EXP2F(sacc[s][4*p+2]-mrun);
        float e3 = EXP2F(sacc[s][4*p+3]-mrun);
        ps += (e0+e1)+(e2+e3);
        Wp[s][p][0] = cvtpk(e0,e1);
        Wp[s][p][1] = cvtpk(e2,e3);
      }
    ps = cross_sum(ps);
    lrun += ps;

    // single wait for all tr-reads (issued pre-softmax), then pure-reg PV
    asm volatile("s_waitcnt lgkmcnt(0)");
    __builtin_amdgcn_sched_barrier(0);
    __builtin_amdgcn_s_setprio(1);
#pragma unroll
    for (int kc=0; kc<4; ++kc){
      int s = kc>>1, pA = (2*kc)&3, pB = (2*kc+1)&3;
      auto r0 = __builtin_amdgcn_permlane32_swap(Wp[s][pA][0], Wp[s][pB][0], false, false);
      auto r1 = __builtin_amdgcn_permlane32_swap(Wp[s][pA][1], Wp[s][pB][1], false, false);
      union { u32 w[4]; short8 s8; } bp;
      bp.w[0]=r0[0]; bp.w[1]=r1[0]; bp.w[2]=r0[1]; bp.w[3]=r1[1];
      union { uint2 u2[2]; short8 s8; } a0, a1;
      a0.u2[0]=av[kc][0][0]; a0.u2[1]=av[kc][0][1];
      a1.u2[0]=av[kc][1][0]; a1.u2[1]=av[kc][1][1];
      oacc[0] = MFMA32(a0.s8, bp.s8, oacc[0]);
      oacc[1] = MFMA32(a1.s8, bp.s8, oacc[1]);
    }
    __builtin_amdgcn_s_setprio(0);
    cur ^= 1;
  }

  if (split){
    // unnormalized partial O^T + (m,l) per q
    u16* po = Opart + (size_t)cid*8192 + (wid*32 + q5)*64;
#pragma unroll
    for (int dblk=0; dblk<2; ++dblk)
#pragma unroll
      for (int p=0;p<4;++p){
        int d0 = 32*dblk + 8*p + 4*hi;
        union { uint2 u; u16 hh[4]; } o;
#pragma unroll
        for (int r=0;r<4;++r) o.hh[r] = f2bf(oacc[dblk][4*p+r]);
        *(uint2*)(po + d0) = o.u;
      }
    if (lane < 32){
      ml[((size_t)cid*128 + wid*32 + q5)*2 + 0] = mrun;
      ml[((size_t)cid*128 + wid*32 + q5)*2 + 1] = lrun;
    }
  } else {
    float rcp = 1.f / lrun;
#pragma unroll
    for (int dblk=0; dblk<2; ++dblk)
#pragma unroll
      for (int p=0;p<4;++p){
        int d0 = 32*dblk + 8*p + 4*hi;
        union { uint2 u; u16 hh[4]; } o;
#pragma unroll
        for (int r=0;r<4;++r) o.hh[r] = f2bf(oacc[dblk][4*p+r] * rcp);
        *(uint2*)(O + (size_t)qrow*1024 + vbh + d0) = o.u;
      }
  }
#undef STAGE
}

// ---------------- combine: merge 2 kv-chunks for qt>=8 -----------------------
__global__ __launch_bounds__(128)
void attn_combine(const u16* __restrict__ Opart, const float* __restrict__ ml,
                  u16* __restrict__ O)
{
  int cb = blockIdx.x >> 4;                  // 0..23
  int qt = 31 - cb;                          // 31..8
  int bh = blockIdx.x & 15;
  int b = bh>>3, h = bh&7;
  int q = threadIdx.x;                       // 0..127
  int cid0 = (cb*2)*16 + bh, cid1 = cid0 + 16;
  float m0 = ml[((size_t)cid0*128 + q)*2], l0 = ml[((size_t)cid0*128 + q)*2 + 1];
  float m1 = ml[((size_t)cid1*128 + q)*2], l1 = ml[((size_t)cid1*128 + q)*2 + 1];
  float mx = fmaxf(m0, m1);
  float w0 = EXP2F(m0 - mx), w1 = EXP2F(m1 - mx);
  float rcp = 1.f / (w0*l0 + w1*l1);
  w0 *= rcp; w1 *= rcp;
  const u16* p0 = Opart + ((size_t)cid0*128 + q)*64;
  const u16* p1 = Opart + ((size_t)cid1*128 + q)*64;
  u16* o = O + (size_t)(qt*128 + q)*1024 + b*512 + h*64;
#pragma unroll
  for (int d0=0; d0<64; d0+=8){
    union { uint4 v; u16 s[8]; } a, c, r;
    a.v = *(const uint4*)(p0 + d0);
    c.v = *(const uint4*)(p1 + d0);
#pragma unroll
    for (int j=0;j<8;j++) r.s[j] = f2bf(w0*bf2f(a.s[j]) + w1*bf2f(c.s[j]));
    *(uint4*)(o + d0) = r.v;
  }
}

// ---------------- launch ----------------
extern "C" void kernel_launch(void* const* d_in, const int* in_sizes, int n_in,
                              void* d_out, int out_size, void* d_ws, size_t ws_size,
                              hipStream_t stream)
{
  float* out = (float*)d_out;
  const float* src_f = (const float*)d_in[0];
  char* ws = (char*)d_ws;
  const size_t MB = 1024ull*1024ull;
  u16* xbuf = (u16*)(ws);            // [0,8)   x ; later attn-out
  u16* xr   = (u16*)(ws +  8*MB);    // [8,16)  RoPE(x) ; later src2
  u16* qkv  = (u16*)(ws + 16*MB);    // [16,40) fused Q|K|V [8192][1536]
  u16* y2   = (u16*)(ws + 16*MB);    // [16,24) LN2 out (qkv dead by then)
  u16* hb   = (u16*)(ws + 24*MB);    // [24,56) FFN hidden
  u16* opart= (u16*)(ws + 40*MB);    // [40,52) attn partials (dead before FFN1)
  float* mlb= (float*)(ws + 52*MB);  // [52,52.75) m/l partials
  u16* arena= (u16*)(ws + 56*MB);    // ~7.33MB converted bf16 weights
  u16* attn = xbuf;
  u16* src2 = xr;

  ConvArgs ca;
  u16* cv[15]; cv[0] = nullptr;
  {
    size_t off = 0; int blk = 0;
    for (int i=1;i<15;i++){
      cv[i] = arena + off;
      int n = in_sizes[i];
      ca.in[i-1]  = (const float4*)d_in[i];
      ca.out[i-1] = (uint2*)cv[i];
      ca.n4[i-1]  = n >> 2;
      ca.sb[i-1]  = blk;
      blk += ((n>>2) + 255) / 256;
      off += (size_t)n;
    }
    ca.sb[14] = blk;
    conv_all<<<blk, 256, 0, stream>>>(ca);
  }
  const u16* rcos = cv[1];
  const u16* rsin = cv[2];
  const u16* inw  = cv[3];
  const u16* inb  = cv[4];
  const u16* outw = cv[5];
  const u16* outb = cv[6];
  const u16* w1   = cv[7];
  const u16* b1   = cv[8];
  const u16* w2   = cv[9];
  const u16* b2   = cv[10];
  const u16* ln1w = cv[11];
  const u16* ln1b = cv[12];
  const u16* ln2w = cv[13];
  const u16* ln2b = cv[14];

  ln_kernel<1,1><<<2048, 256, 0, stream>>>(src_f, ln1w, ln1b, rcos, rsin, xbuf, xr);

  // fused Q|K|V projection: A = xr for cols<1024 (bn<8), xbuf for V cols (bn>=8)
  gemm_bt<EPI_NONE,0,0,1,1,128><<<768, 256, 0, stream>>>(xr, inw, inb, xbuf, qkv, 8192, 1536, 512);

  attn_kernel<<<896, 256, 0, stream>>>(qkv, opart, mlb, attn);
  attn_combine<<<384, 128, 0, stream>>>(opart, mlb, attn);

  gemm_bt<EPI_RES,1,0,0,0,64><<<512, 256, 0, stream>>>(attn, outw, outb, src_f, src2, 8192, 512, 512);

  ln_kernel<0,0><<<2048, 256, 0, stream>>>(src2, ln2w, ln2b, nullptr, nullptr, y2, nullptr);

  gemm_bt<EPI_GELU,0,0,0,0,128><<<1024, 256, 0, stream>>>(y2, w1, b1, nullptr, hb, 8192, 2048, 512);
  gemm_bt<EPI_RES,0,1,0,0,64><<<512, 256, 0, stream>>>(hb, w2, b2, src2, out, 8192, 512, 2048);
}

// Round 21
// 191.042 us; speedup vs baseline: 1.0510x; 1.0215x over previous
//
#include <hip/hip_runtime.h>
#include <hip/hip_bf16.h>

typedef unsigned short u16;
typedef unsigned int u32;
using short8 = __attribute__((ext_vector_type(8))) short;
using f32x4  = __attribute__((ext_vector_type(4))) float;
using f32x16 = __attribute__((ext_vector_type(16))) float;

#define MFMA16(a,b,c) __builtin_amdgcn_mfma_f32_16x16x32_bf16((a),(b),(c),0,0,0)
#define MFMA32(a,b,c) __builtin_amdgcn_mfma_f32_32x32x16_bf16((a),(b),(c),0,0,0)
#define EXP2F(x) __builtin_amdgcn_exp2f(x)

__device__ __forceinline__ float bf2f(u16 u){
  union { u32 i; float f; } v; v.i = ((u32)u)<<16; return v.f;
}
__device__ __forceinline__ u16 f2bf(float f){
  u32 x = __float_as_uint(f);
  x += 0x7fffu + ((x>>16)&1u);
  return (u16)(x>>16);
}
__device__ __forceinline__ u32 cvtpk(float lo, float hi){
  u32 r;
  asm("v_cvt_pk_bf16_f32 %0, %1, %2" : "=v"(r) : "v"(lo), "v"(hi));
  return r;
}
// SSA-safe cross-half exchange (lane i <-> lane i+32 halves merged)
__device__ __forceinline__ float cross_max(float v){
  u32 b = __float_as_uint(v);
  auto r = __builtin_amdgcn_permlane32_swap(b, b, false, false);
  return fmaxf(__uint_as_float(r[0]), __uint_as_float(r[1]));
}
__device__ __forceinline__ float cross_sum(float v){
  u32 b = __float_as_uint(v);
  auto r = __builtin_amdgcn_permlane32_swap(b, b, false, false);
  return __uint_as_float(r[0]) + __uint_as_float(r[1]);
}

typedef __attribute__((address_space(1))) const u32 GU32;
typedef __attribute__((address_space(3))) u32 LU32;
typedef __attribute__((address_space(3))) const u16 LDSU16C;
__device__ __forceinline__ void gload_lds16(const void* g, void* l){
  __builtin_amdgcn_global_load_lds((GU32*)g, (LU32*)l, 16, 0, 0);
}

template<int OFF>
__device__ __forceinline__ uint2 tr16(const u16* p){
  uint2 r;
  if constexpr (OFF == 0)
    asm volatile("ds_read_b64_tr_b16 %0, %1" : "=v"(r) : "v"((LDSU16C*)p));
  else
    asm volatile("ds_read_b64_tr_b16 %0, %1 offset:128" : "=v"(r) : "v"((LDSU16C*)p));
  return r;
}

// ---------------- fused fp32 -> bf16 converter ----------------
struct ConvArgs {
  const float4* in[14];
  uint2* out[14];
  int n4[14];
  int sb[15];
};
__global__ __launch_bounds__(256)
void conv_all(ConvArgs a)
{
  int bid = blockIdx.x;
  int s = 0;
  while (s < 13 && bid >= a.sb[s+1]) ++s;
  int i = (bid - a.sb[s])*256 + threadIdx.x;
  if (i >= a.n4[s]) return;
  float4 v = a.in[s][i];
  union { uint2 u; u16 h[4]; } o;
  o.h[0] = f2bf(v.x); o.h[1] = f2bf(v.y);
  o.h[2] = f2bf(v.z); o.h[3] = f2bf(v.w);
  a.out[s][i] = o.u;
}

// ---------------- LayerNorm (+ optional RoPE) ----------------
template<int DO_ROPE, int IN_F32>
__global__ __launch_bounds__(256)
void ln_kernel(const void* __restrict__ inv, const u16* __restrict__ lw,
               const u16* __restrict__ lb, const u16* __restrict__ ct,
               const u16* __restrict__ st, u16* __restrict__ xo,
               u16* __restrict__ xro)
{
  __shared__ float xs[4][512];
  int tid = threadIdx.x, wid = tid>>6, lane = tid&63;
  int m = blockIdx.x*4 + wid;
  int d0 = lane*8;
  float v[8], sum = 0.f, sq = 0.f;
  if (IN_F32){
    const float* in = (const float*)inv;
    float4 a = *(const float4*)(in + (size_t)m*512 + d0);
    float4 b = *(const float4*)(in + (size_t)m*512 + d0 + 4);
    v[0]=a.x; v[1]=a.y; v[2]=a.z; v[3]=a.w;
    v[4]=b.x; v[5]=b.y; v[6]=b.z; v[7]=b.w;
  } else {
    const u16* in = (const u16*)inv;
    union { uint4 q; u16 s[8]; } pk;
    pk.q = *(const uint4*)(in + (size_t)m*512 + d0);
#pragma unroll
    for (int j=0;j<8;j++) v[j] = bf2f(pk.s[j]);
  }
#pragma unroll
  for (int j=0;j<8;j++){ sum+=v[j]; sq+=v[j]*v[j]; }
#pragma unroll
  for (int o=1;o<64;o<<=1){ sum += __shfl_xor(sum,o); sq += __shfl_xor(sq,o); }
  float mean = sum*(1.f/512.f);
  float var  = sq*(1.f/512.f) - mean*mean;
  float rstd = rsqrtf(var + 1e-5f);
  float xn[8];
  union { uint4 q; u16 s[8]; } ou;
#pragma unroll
  for (int j=0;j<8;j++){
    int d = d0+j;
    xn[j] = (v[j]-mean)*rstd*bf2f(lw[d]) + bf2f(lb[d]);
    ou.s[j] = f2bf(xn[j]);
  }
  *(uint4*)(xo + (size_t)m*512 + d0) = ou.q;
  if (DO_ROPE){
#pragma unroll
    for (int j=0;j<8;j++) xs[wid][d0+j] = xn[j];
    __syncthreads();
    int si = m>>1;
    int hb = d0 & ~63;
#pragma unroll
    for (int j=0;j<8;j++){
      int d = d0+j, jh = d&63;
      float rh = (jh<32) ? -xs[wid][hb + 2*jh+1] : xs[wid][hb + 2*(jh-32)];
      float c  = bf2f(ct[si*64+jh]);
      float s2 = bf2f(st[si*64+jh]);
      ou.s[j] = f2bf(xn[j]*c + rh*s2);
    }
    *(uint4*)(xro + (size_t)m*512 + d0) = ou.q;
  }
}

// ---------------- GEMM: C[M,N] = A[M,K] * W[N,K]^T + bias (+epi) -------------
// BK=64, 32x32x16 MFMA, XOR-swizzled LDS, single-buffered, XCD-chunked grid.
#define EPI_NONE 0
#define EPI_GELU 1
#define EPI_RES  2

// SELA: resv doubles as second A (bn>=8 => V cols of fused QKV). BM: 128 or 64.
template<int EPI, int RES_F32, int OUT_F32, int QSCL, int SELA, int BM>
__global__ __launch_bounds__(256)
void gemm_bt(const u16* __restrict__ A, const u16* __restrict__ W,
             const u16* __restrict__ bias, const void* __restrict__ resv,
             void* __restrict__ Cv, int M, int N, int K)
{
  constexpr int IF = BM/32;          // A-stage issues per wave
  constexpr int RF = BM/64;          // 32-row frags per wave
  __shared__ u16 As[BM*64];
  __shared__ u16 Bs[128*64];
  int tid = threadIdx.x, wid = tid>>6, lane = tid&63;
  int l31 = lane & 31, hi = lane >> 5;
  int nbn = N >> 7;
  // T1 XCD-chunked swizzle (grid % 8 == 0): XCD x owns a contiguous bm range
  int nwg = gridDim.x;
  int swz = (blockIdx.x & 7) * (nwg >> 3) + (blockIdx.x >> 3);
  int bm = swz / nbn, bn = swz % nbn;
  int wr = wid >> 1, wc = wid & 1;
  f32x16 acc[RF][2];
#pragma unroll
  for (int i=0;i<RF;i++)
#pragma unroll
    for (int j=0;j<2;j++)
#pragma unroll
      for (int t=0;t<16;t++) acc[i][j][t] = 0.f;

  const u16* Ap = (SELA && bn >= 8) ? (const u16*)resv : A;
  const u16* Abase = Ap + (size_t)(bm*BM)*K;
  const u16* Wbase = W + (size_t)(bn*128)*K;
  int srow = lane>>3;                          // 0..7 (row within 8-row stripe)
  int schk = ((lane&7) ^ srow) << 3;           // pre-swizzled source chunk (u16)

  for (int kb = 0; kb < K; kb += 64){
    // stage: 8 rows per issue, linear dest, swizzled source
#pragma unroll
    for (int i=0;i<IF;i++){
      int row = wid*(8*IF) + i*8 + srow;
      gload_lds16(Abase + (size_t)row*K + kb + schk, &As[(wid*(8*IF) + i*8)*64]);
    }
#pragma unroll
    for (int i=0;i<4;i++){
      int row = wid*32 + i*8 + srow;
      gload_lds16(Wbase + (size_t)row*K + kb + schk, &Bs[(wid*32 + i*8)*64]);
    }
    __syncthreads();
#pragma unroll
    for (int ks=0; ks<4; ++ks){
      short8 af[RF], bf8[2];
#pragma unroll
      for (int i=0;i<RF;i++){
        int row = wr*(BM/2) + i*32 + l31;
        af[i] = *(const short8*)&As[row*64 + (((2*ks + hi) ^ (row&7))<<3)];
      }
#pragma unroll
      for (int j=0;j<2;j++){
        int colr = wc*64 + j*32 + l31;
        bf8[j] = *(const short8*)&Bs[colr*64 + (((2*ks + hi) ^ (colr&7))<<3)];
      }
#pragma unroll
      for (int i=0;i<RF;i++)
#pragma unroll
        for (int j=0;j<2;j++)
          acc[i][j] = MFMA32(af[i], bf8[j], acc[i][j]);
    }
    __syncthreads();
  }
  // epilogue: C row = (t&3)+8*(t>>2)+4*hi (A-operand), col = l31 (B-operand)
#pragma unroll
  for (int i=0;i<RF;i++){
#pragma unroll
    for (int j=0;j<2;j++){
      int col = bn*128 + wc*64 + j*32 + l31;
      float bv = bf2f(bias[col]);
#pragma unroll
      for (int t=0;t<16;t++){
        int row = bm*BM + wr*(BM/2) + i*32 + (t&3) + 8*(t>>2) + 4*hi;
        size_t idx = (size_t)row*N + col;
        float x = acc[i][j][t] + bv;
        if (EPI == EPI_GELU) x = 0.5f*x*(1.f + erff(x*0.70710678118f));
        if (EPI == EPI_RES){
          if (RES_F32) x += ((const float*)resv)[idx];
          else         x += bf2f(((const u16*)resv)[idx]);
        }
        if (QSCL && col < 512) x *= 0.18033688011f;  // 0.125*log2(e): softmax exp2 domain
        if (OUT_F32) ((float*)Cv)[idx] = x;
        else         ((u16*)Cv)[idx]   = f2bf(x);
      }
    }
  }
}

// ---------------- Causal flash attention: split-kv, KVBLK=64, 32KB LDS ------
// QKV layout [4096][2][1536]: Q cols 0..511, K 512..1023, V 1024..1535.
// grid 896: bid<768: split chunks (qt>=8, 2 kv-halves, heavy first) -> partials
//           bid>=768: direct rows (qt=7..0) -> O
// launch_bounds(256,3): 170-reg budget -> full tr16 hoist fits (no spill).
__global__ __launch_bounds__(256, 3)
void attn_kernel(const u16* __restrict__ QKV, u16* __restrict__ Opart,
                 float* __restrict__ ml, u16* __restrict__ O)
{
  __shared__ u16 Ks[2][64*64];      // 8KB each, swizzled: LDS(r,cb)=K(r, cb^((r&7)<<4))
  __shared__ u16 Vp[2][4*1024];     // 8KB each, 4 panels [64 kv][16 d]
  int tid = threadIdx.x, wid = tid>>6, lane = tid&63;
  int l15 = lane&15, q5 = lane&31, hi = lane>>5;
  int bid = blockIdx.x;
  int qt, kt0, kt1, cid = bid;
  bool split = (bid < 768);
  if (split){
    int idx = bid >> 4;              // 0..47 heavy-first
    qt = 31 - (idx >> 1);            // 31..8
    int half = idx & 1;
    int nk = 2*qt + 2, h0 = nk >> 1; // qt+1
    kt0 = half ? h0 : 0; kt1 = half ? nk : h0;
  } else {
    qt = 7 - ((bid - 768) >> 4);
    kt0 = 0; kt1 = 2*qt + 2;
  }
  int bh = bid & 15;
  int b = bh>>3, h = bh&7;
  size_t qkvb = (size_t)b*1536 + h*64;
  size_t vbh  = (size_t)b*512  + h*64;

  int qrow = qt*128 + wid*32 + q5;        // this lane's q (column of S^T/O^T)
  short8 aQ[4];
#pragma unroll
  for (int kc=0; kc<4; ++kc)
    aQ[kc] = *(const short8*)(QKV + (size_t)qrow*3072 + qkvb + 16*kc + 8*hi);

  f32x16 oacc[2];
#pragma unroll
  for (int dblk=0; dblk<2; ++dblk)
#pragma unroll
    for (int r=0;r<16;r++) oacc[dblk][r] = 0.f;
  float mrun = -3e38f, lrun = 0.f;

#define STAGE(KT, BUF)                                                              \
  {                                                                                 \
    _Pragma("unroll")                                                               \
    for (int i=0;i<2;++i){                                                          \
      gload_lds16(QKV + (size_t)((KT)*64 + wid*16 + i*8 + (lane>>3))*3072 + qkvb    \
                      + 512 + (((lane&7)^(lane>>3))<<3),                            \
                  &Ks[BUF][(wid*16 + i*8)*64]);                                     \
      int j = wid*2 + i, p = j>>1, rh = (j&1)*32;                                   \
      gload_lds16(QKV + (size_t)((KT)*64 + rh + (lane>>1))*3072 + qkvb              \
                      + 1024 + p*16 + ((lane&1)<<3),                                \
                  &Vp[BUF][p*1024 + rh*16]);                                        \
    }                                                                               \
  }

  STAGE(kt0, 0);
  int cur = 0;

  for (int kt=kt0; kt<kt1; ++kt){
    __syncthreads();                 // drains DMA -> buf[cur] ready
    if (kt+1 < kt1) STAGE(kt+1, cur^1);

    // S^T = K @ Q^T : col=q5, 2 sub-accs of 32 kv rows
    f32x16 sacc[2];
#pragma unroll
    for (int s=0;s<2;s++)
#pragma unroll
      for (int r=0;r<16;r++) sacc[s][r] = 0.f;
    __builtin_amdgcn_s_setprio(1);
#pragma unroll
    for (int kc=0; kc<4; ++kc)
#pragma unroll
      for (int s=0; s<2; ++s){
        int cb = (32*kc + 16*hi) ^ ((q5&7)<<4);   // bytes, XOR read swizzle
        short8 aK = *(const short8*)&Ks[cur][(32*s + q5)*64 + (cb>>1)];
        sacc[s] = MFMA32(aK, aQ[kc], sacc[s]);
      }
    __builtin_amdgcn_s_setprio(0);

    // issue ALL V transpose-reads now; LDS latency hides under softmax (32 VGPR)
    uint2 av[4][2][2];
#pragma unroll
    for (int kc=0; kc<4; ++kc)
#pragma unroll
      for (int dblk=0; dblk<2; ++dblk){
        const u16* base = &Vp[cur][(((lane>>4)&1) + 2*dblk)*1024 + (16*kc + 8*hi)*16 + l15*4];
        av[kc][dblk][0] = tr16<0>(base);
        av[kc][dblk][1] = tr16<128>(base);
      }

    // lane-local online softmax (values pre-scaled into exp2 domain)
    bool diag = (kt >= 2*qt);
    float pm[4] = {-3e38f,-3e38f,-3e38f,-3e38f};
#pragma unroll
    for (int s=0;s<2;++s)
#pragma unroll
      for (int r=0;r<16;++r){
        float x = sacc[s][r];
        if (diag){
          int kv = kt*64 + 32*s + (r&3) + 8*(r>>2) + 4*hi;
          if (kv > qrow) x = -3e38f;
          sacc[s][r] = x;
        }
        pm[r&3] = fmaxf(pm[r&3], x);
      }
    float pmax = fmaxf(fmaxf(pm[0],pm[1]), fmaxf(pm[2],pm[3]));
    pmax = cross_max(pmax);
    // T13 defer-max: only rescale when max grew by > 8 (P bounded by 2^8)
    if (!__all(pmax <= mrun + 8.f)){
      float mn = fmaxf(mrun, pmax);
      float alpha = EXP2F(mrun - mn);
      mrun = mn;
      lrun *= alpha;
#pragma unroll
      for (int dblk=0; dblk<2; ++dblk)
#pragma unroll
        for (int r=0;r<16;++r) oacc[dblk][r] *= alpha;
    }
    float ps = 0.f;
    u32 Wp[2][4][2];
#pragma unroll
    for (int s=0;s<2;++s)
#pragma unroll
      for (int p=0;p<4;++p){
        float e0 = EXP2F(sacc[s][4*p+0]-mrun);
        float e1 = EXP2F(sacc[s][4*p+1]-mrun);
        float e2 = EXP2F(sacc[s][4*p+2]-mrun);
        float e3 = EXP2F(sacc[s][4*p+3]-mrun);
        ps += (e0+e1)+(e2+e3);
        Wp[s][p][0] = cvtpk(e0,e1);
        Wp[s][p][1] = cvtpk(e2,e3);
      }
    ps = cross_sum(ps);
    lrun += ps;

    // single wait for all tr-reads (issued pre-softmax), then pure-reg PV
    asm volatile("s_waitcnt lgkmcnt(0)");
    __builtin_amdgcn_sched_barrier(0);
    __builtin_amdgcn_s_setprio(1);
#pragma unroll
    for (int kc=0; kc<4; ++kc){
      int s = kc>>1, pA = (2*kc)&3, pB = (2*kc+1)&3;
      auto r0 = __builtin_amdgcn_permlane32_swap(Wp[s][pA][0], Wp[s][pB][0], false, false);
      auto r1 = __builtin_amdgcn_permlane32_swap(Wp[s][pA][1], Wp[s][pB][1], false, false);
      union { u32 w[4]; short8 s8; } bp;
      bp.w[0]=r0[0]; bp.w[1]=r1[0]; bp.w[2]=r0[1]; bp.w[3]=r1[1];
      union { uint2 u2[2]; short8 s8; } a0, a1;
      a0.u2[0]=av[kc][0][0]; a0.u2[1]=av[kc][0][1];
      a1.u2[0]=av[kc][1][0]; a1.u2[1]=av[kc][1][1];
      oacc[0] = MFMA32(a0.s8, bp.s8, oacc[0]);
      oacc[1] = MFMA32(a1.s8, bp.s8, oacc[1]);
    }
    __builtin_amdgcn_s_setprio(0);
    cur ^= 1;
  }

  if (split){
    // unnormalized partial O^T + (m,l) per q
    u16* po = Opart + (size_t)cid*8192 + (wid*32 + q5)*64;
#pragma unroll
    for (int dblk=0; dblk<2; ++dblk)
#pragma unroll
      for (int p=0;p<4;++p){
        int d0 = 32*dblk + 8*p + 4*hi;
        union { uint2 u; u16 hh[4]; } o;
#pragma unroll
        for (int r=0;r<4;++r) o.hh[r] = f2bf(oacc[dblk][4*p+r]);
        *(uint2*)(po + d0) = o.u;
      }
    if (lane < 32){
      ml[((size_t)cid*128 + wid*32 + q5)*2 + 0] = mrun;
      ml[((size_t)cid*128 + wid*32 + q5)*2 + 1] = lrun;
    }
  } else {
    float rcp = 1.f / lrun;
#pragma unroll
    for (int dblk=0; dblk<2; ++dblk)
#pragma unroll
      for (int p=0;p<4;++p){
        int d0 = 32*dblk + 8*p + 4*hi;
        union { uint2 u; u16 hh[4]; } o;
#pragma unroll
        for (int r=0;r<4;++r) o.hh[r] = f2bf(oacc[dblk][4*p+r] * rcp);
        *(uint2*)(O + (size_t)qrow*1024 + vbh + d0) = o.u;
      }
  }
#undef STAGE
}

// ---------------- combine: merge 2 kv-chunks for qt>=8 -----------------------
__global__ __launch_bounds__(128)
void attn_combine(const u16* __restrict__ Opart, const float* __restrict__ ml,
                  u16* __restrict__ O)
{
  int cb = blockIdx.x >> 4;                  // 0..23
  int qt = 31 - cb;                          // 31..8
  int bh = blockIdx.x & 15;
  int b = bh>>3, h = bh&7;
  int q = threadIdx.x;                       // 0..127
  int cid0 = (cb*2)*16 + bh, cid1 = cid0 + 16;
  float m0 = ml[((size_t)cid0*128 + q)*2], l0 = ml[((size_t)cid0*128 + q)*2 + 1];
  float m1 = ml[((size_t)cid1*128 + q)*2], l1 = ml[((size_t)cid1*128 + q)*2 + 1];
  float mx = fmaxf(m0, m1);
  float w0 = EXP2F(m0 - mx), w1 = EXP2F(m1 - mx);
  float rcp = 1.f / (w0*l0 + w1*l1);
  w0 *= rcp; w1 *= rcp;
  const u16* p0 = Opart + ((size_t)cid0*128 + q)*64;
  const u16* p1 = Opart + ((size_t)cid1*128 + q)*64;
  u16* o = O + (size_t)(qt*128 + q)*1024 + b*512 + h*64;
#pragma unroll
  for (int d0=0; d0<64; d0+=8){
    union { uint4 v; u16 s[8]; } a, c, r;
    a.v = *(const uint4*)(p0 + d0);
    c.v = *(const uint4*)(p1 + d0);
#pragma unroll
    for (int j=0;j<8;j++) r.s[j] = f2bf(w0*bf2f(a.s[j]) + w1*bf2f(c.s[j]));
    *(uint4*)(o + d0) = r.v;
  }
}

// ---------------- launch ----------------
extern "C" void kernel_launch(void* const* d_in, const int* in_sizes, int n_in,
                              void* d_out, int out_size, void* d_ws, size_t ws_size,
                              hipStream_t stream)
{
  float* out = (float*)d_out;
  const float* src_f = (const float*)d_in[0];
  char* ws = (char*)d_ws;
  const size_t MB = 1024ull*1024ull;
  u16* xbuf = (u16*)(ws);            // [0,8)   x ; later attn-out
  u16* xr   = (u16*)(ws +  8*MB);    // [8,16)  RoPE(x) ; later src2
  u16* qkv  = (u16*)(ws + 16*MB);    // [16,40) fused Q|K|V [8192][1536]
  u16* y2   = (u16*)(ws + 16*MB);    // [16,24) LN2 out (qkv dead by then)
  u16* hb   = (u16*)(ws + 24*MB);    // [24,56) FFN hidden
  u16* opart= (u16*)(ws + 40*MB);    // [40,52) attn partials (dead before FFN1)
  float* mlb= (float*)(ws + 52*MB);  // [52,52.75) m/l partials
  u16* arena= (u16*)(ws + 56*MB);    // ~7.33MB converted bf16 weights
  u16* attn = xbuf;
  u16* src2 = xr;

  ConvArgs ca;
  u16* cv[15]; cv[0] = nullptr;
  {
    size_t off = 0; int blk = 0;
    for (int i=1;i<15;i++){
      cv[i] = arena + off;
      int n = in_sizes[i];
      ca.in[i-1]  = (const float4*)d_in[i];
      ca.out[i-1] = (uint2*)cv[i];
      ca.n4[i-1]  = n >> 2;
      ca.sb[i-1]  = blk;
      blk += ((n>>2) + 255) / 256;
      off += (size_t)n;
    }
    ca.sb[14] = blk;
    conv_all<<<blk, 256, 0, stream>>>(ca);
  }
  const u16* rcos = cv[1];
  const u16* rsin = cv[2];
  const u16* inw  = cv[3];
  const u16* inb  = cv[4];
  const u16* outw = cv[5];
  const u16* outb = cv[6];
  const u16* w1   = cv[7];
  const u16* b1   = cv[8];
  const u16* w2   = cv[9];
  const u16* b2   = cv[10];
  const u16* ln1w = cv[11];
  const u16* ln1b = cv[12];
  const u16* ln2w = cv[13];
  const u16* ln2b = cv[14];

  ln_kernel<1,1><<<2048, 256, 0, stream>>>(src_f, ln1w, ln1b, rcos, rsin, xbuf, xr);

  // fused Q|K|V projection: A = xr for cols<1024 (bn<8), xbuf for V cols (bn>=8)
  gemm_bt<EPI_NONE,0,0,1,1,128><<<768, 256, 0, stream>>>(xr, inw, inb, xbuf, qkv, 8192, 1536, 512);

  attn_kernel<<<896, 256, 0, stream>>>(qkv, opart, mlb, attn);
  attn_combine<<<384, 128, 0, stream>>>(opart, mlb, attn);

  gemm_bt<EPI_RES,1,0,0,0,64><<<512, 256, 0, stream>>>(attn, outw, outb, src_f, src2, 8192, 512, 512);

  ln_kernel<0,0><<<2048, 256, 0, stream>>>(src2, ln2w, ln2b, nullptr, nullptr, y2, nullptr);

  gemm_bt<EPI_GELU,0,0,0,0,128><<<1024, 256, 0, stream>>>(y2, w1, b1, nullptr, hb, 8192, 2048, 512);
  gemm_bt<EPI_RES,0,1,0,0,64><<<512, 256, 0, stream>>>(hb, w2, b2, src2, out, 8192, 512, 2048);
}

// Round 22
// 188.981 us; speedup vs baseline: 1.0625x; 1.0109x over previous
//
#include <hip/hip_runtime.h>
#include <hip/hip_bf16.h>

typedef unsigned short u16;
typedef unsigned int u32;
using short8 = __attribute__((ext_vector_type(8))) short;
using f32x4  = __attribute__((ext_vector_type(4))) float;
using f32x16 = __attribute__((ext_vector_type(16))) float;

#define MFMA16(a,b,c) __builtin_amdgcn_mfma_f32_16x16x32_bf16((a),(b),(c),0,0,0)
#define MFMA32(a,b,c) __builtin_amdgcn_mfma_f32_32x32x16_bf16((a),(b),(c),0,0,0)
#define EXP2F(x) __builtin_amdgcn_exp2f(x)

__device__ __forceinline__ float bf2f(u16 u){
  union { u32 i; float f; } v; v.i = ((u32)u)<<16; return v.f;
}
__device__ __forceinline__ u16 f2bf(float f){
  u32 x = __float_as_uint(f);
  x += 0x7fffu + ((x>>16)&1u);
  return (u16)(x>>16);
}
__device__ __forceinline__ u32 cvtpk(float lo, float hi){
  u32 r;
  asm("v_cvt_pk_bf16_f32 %0, %1, %2" : "=v"(r) : "v"(lo), "v"(hi));
  return r;
}
// SSA-safe cross-half exchange (lane i <-> lane i+32 halves merged)
__device__ __forceinline__ float cross_max(float v){
  u32 b = __float_as_uint(v);
  auto r = __builtin_amdgcn_permlane32_swap(b, b, false, false);
  return fmaxf(__uint_as_float(r[0]), __uint_as_float(r[1]));
}
__device__ __forceinline__ float cross_sum(float v){
  u32 b = __float_as_uint(v);
  auto r = __builtin_amdgcn_permlane32_swap(b, b, false, false);
  return __uint_as_float(r[0]) + __uint_as_float(r[1]);
}

typedef __attribute__((address_space(1))) const u32 GU32;
typedef __attribute__((address_space(3))) u32 LU32;
typedef __attribute__((address_space(3))) const u16 LDSU16C;
__device__ __forceinline__ void gload_lds16(const void* g, void* l){
  __builtin_amdgcn_global_load_lds((GU32*)g, (LU32*)l, 16, 0, 0);
}

template<int OFF>
__device__ __forceinline__ uint2 tr16(const u16* p){
  uint2 r;
  if constexpr (OFF == 0)
    asm volatile("ds_read_b64_tr_b16 %0, %1" : "=v"(r) : "v"((LDSU16C*)p));
  else
    asm volatile("ds_read_b64_tr_b16 %0, %1 offset:128" : "=v"(r) : "v"((LDSU16C*)p));
  return r;
}

// ---------------- fused fp32 -> bf16 converter ----------------
struct ConvArgs {
  const float4* in[14];
  uint2* out[14];
  int n4[14];
  int sb[15];
};
__global__ __launch_bounds__(256)
void conv_all(ConvArgs a)
{
  int bid = blockIdx.x;
  int s = 0;
  while (s < 13 && bid >= a.sb[s+1]) ++s;
  int i = (bid - a.sb[s])*256 + threadIdx.x;
  if (i >= a.n4[s]) return;
  float4 v = a.in[s][i];
  union { uint2 u; u16 h[4]; } o;
  o.h[0] = f2bf(v.x); o.h[1] = f2bf(v.y);
  o.h[2] = f2bf(v.z); o.h[3] = f2bf(v.w);
  a.out[s][i] = o.u;
}

// ---------------- LayerNorm (+ optional RoPE) ----------------
template<int DO_ROPE, int IN_F32>
__global__ __launch_bounds__(256)
void ln_kernel(const void* __restrict__ inv, const u16* __restrict__ lw,
               const u16* __restrict__ lb, const u16* __restrict__ ct,
               const u16* __restrict__ st, u16* __restrict__ xo,
               u16* __restrict__ xro)
{
  __shared__ float xs[4][512];
  int tid = threadIdx.x, wid = tid>>6, lane = tid&63;
  int m = blockIdx.x*4 + wid;
  int d0 = lane*8;
  float v[8], sum = 0.f, sq = 0.f;
  if (IN_F32){
    const float* in = (const float*)inv;
    float4 a = *(const float4*)(in + (size_t)m*512 + d0);
    float4 b = *(const float4*)(in + (size_t)m*512 + d0 + 4);
    v[0]=a.x; v[1]=a.y; v[2]=a.z; v[3]=a.w;
    v[4]=b.x; v[5]=b.y; v[6]=b.z; v[7]=b.w;
  } else {
    const u16* in = (const u16*)inv;
    union { uint4 q; u16 s[8]; } pk;
    pk.q = *(const uint4*)(in + (size_t)m*512 + d0);
#pragma unroll
    for (int j=0;j<8;j++) v[j] = bf2f(pk.s[j]);
  }
#pragma unroll
  for (int j=0;j<8;j++){ sum+=v[j]; sq+=v[j]*v[j]; }
#pragma unroll
  for (int o=1;o<64;o<<=1){ sum += __shfl_xor(sum,o); sq += __shfl_xor(sq,o); }
  float mean = sum*(1.f/512.f);
  float var  = sq*(1.f/512.f) - mean*mean;
  float rstd = rsqrtf(var + 1e-5f);
  float xn[8];
  union { uint4 q; u16 s[8]; } ou;
#pragma unroll
  for (int j=0;j<8;j++){
    int d = d0+j;
    xn[j] = (v[j]-mean)*rstd*bf2f(lw[d]) + bf2f(lb[d]);
    ou.s[j] = f2bf(xn[j]);
  }
  *(uint4*)(xo + (size_t)m*512 + d0) = ou.q;
  if (DO_ROPE){
#pragma unroll
    for (int j=0;j<8;j++) xs[wid][d0+j] = xn[j];
    __syncthreads();
    int si = m>>1;
    int hb = d0 & ~63;
#pragma unroll
    for (int j=0;j<8;j++){
      int d = d0+j, jh = d&63;
      float rh = (jh<32) ? -xs[wid][hb + 2*jh+1] : xs[wid][hb + 2*(jh-32)];
      float c  = bf2f(ct[si*64+jh]);
      float s2 = bf2f(st[si*64+jh]);
      ou.s[j] = f2bf(xn[j]*c + rh*s2);
    }
    *(uint4*)(xro + (size_t)m*512 + d0) = ou.q;
  }
}

// ---------------- GEMM: C[M,N] = A[M,K] * W[N,K]^T + bias (+epi) -------------
// BK=64, 32x32x16 MFMA, XOR-swizzled LDS, single-buffered, XCD-chunked grid.
#define EPI_NONE 0
#define EPI_GELU 1
#define EPI_RES  2

// SELA: resv doubles as second A (bn>=8 => V cols of fused QKV). BM: 128 or 64.
template<int EPI, int RES_F32, int OUT_F32, int QSCL, int SELA, int BM>
__global__ __launch_bounds__(256)
void gemm_bt(const u16* __restrict__ A, const u16* __restrict__ W,
             const u16* __restrict__ bias, const void* __restrict__ resv,
             void* __restrict__ Cv, int M, int N, int K)
{
  constexpr int IF = BM/32;          // A-stage issues per wave
  constexpr int RF = BM/64;          // 32-row frags per wave
  __shared__ u16 As[BM*64];
  __shared__ u16 Bs[128*64];
  int tid = threadIdx.x, wid = tid>>6, lane = tid&63;
  int l31 = lane & 31, hi = lane >> 5;
  int nbn = N >> 7;
  // T1 XCD-chunked swizzle (grid % 8 == 0): XCD x owns a contiguous bm range
  int nwg = gridDim.x;
  int swz = (blockIdx.x & 7) * (nwg >> 3) + (blockIdx.x >> 3);
  int bm = swz / nbn, bn = swz % nbn;
  int wr = wid >> 1, wc = wid & 1;
  f32x16 acc[RF][2];
#pragma unroll
  for (int i=0;i<RF;i++)
#pragma unroll
    for (int j=0;j<2;j++)
#pragma unroll
      for (int t=0;t<16;t++) acc[i][j][t] = 0.f;

  const u16* Ap = (SELA && bn >= 8) ? (const u16*)resv : A;
  const u16* Abase = Ap + (size_t)(bm*BM)*K;
  const u16* Wbase = W + (size_t)(bn*128)*K;
  int srow = lane>>3;                          // 0..7 (row within 8-row stripe)
  int schk = ((lane&7) ^ srow) << 3;           // pre-swizzled source chunk (u16)

  for (int kb = 0; kb < K; kb += 64){
    // stage: 8 rows per issue, linear dest, swizzled source
#pragma unroll
    for (int i=0;i<IF;i++){
      int row = wid*(8*IF) + i*8 + srow;
      gload_lds16(Abase + (size_t)row*K + kb + schk, &As[(wid*(8*IF) + i*8)*64]);
    }
#pragma unroll
    for (int i=0;i<4;i++){
      int row = wid*32 + i*8 + srow;
      gload_lds16(Wbase + (size_t)row*K + kb + schk, &Bs[(wid*32 + i*8)*64]);
    }
    __syncthreads();
#pragma unroll
    for (int ks=0; ks<4; ++ks){
      short8 af[RF], bf8[2];
#pragma unroll
      for (int i=0;i<RF;i++){
        int row = wr*(BM/2) + i*32 + l31;
        af[i] = *(const short8*)&As[row*64 + (((2*ks + hi) ^ (row&7))<<3)];
      }
#pragma unroll
      for (int j=0;j<2;j++){
        int colr = wc*64 + j*32 + l31;
        bf8[j] = *(const short8*)&Bs[colr*64 + (((2*ks + hi) ^ (colr&7))<<3)];
      }
#pragma unroll
      for (int i=0;i<RF;i++)
#pragma unroll
        for (int j=0;j<2;j++)
          acc[i][j] = MFMA32(af[i], bf8[j], acc[i][j]);
    }
    __syncthreads();
  }
  // epilogue: C row = (t&3)+8*(t>>2)+4*hi (A-operand), col = l31 (B-operand)
#pragma unroll
  for (int i=0;i<RF;i++){
#pragma unroll
    for (int j=0;j<2;j++){
      int col = bn*128 + wc*64 + j*32 + l31;
      float bv = bf2f(bias[col]);
#pragma unroll
      for (int t=0;t<16;t++){
        int row = bm*BM + wr*(BM/2) + i*32 + (t&3) + 8*(t>>2) + 4*hi;
        size_t idx = (size_t)row*N + col;
        float x = acc[i][j][t] + bv;
        if (EPI == EPI_GELU) x = 0.5f*x*(1.f + erff(x*0.70710678118f));
        if (EPI == EPI_RES){
          if (RES_F32) x += ((const float*)resv)[idx];
          else         x += bf2f(((const u16*)resv)[idx]);
        }
        if (QSCL && col < 512) x *= 0.18033688011f;  // 0.125*log2(e): softmax exp2 domain
        if (OUT_F32) ((float*)Cv)[idx] = x;
        else         ((u16*)Cv)[idx]   = f2bf(x);
      }
    }
  }
}

// ---------------- Causal flash attention: split-kv, KVBLK=64, 32KB LDS ------
// QKV layout [4096][2][1536]: Q cols 0..511, K 512..1023, V 1024..1535.
// grid 896: bid<768: split chunks (qt>=8, 2 kv-halves, heavy first) -> partials
//           bid>=768: direct rows (qt=7..0) -> O
// launch_bounds(256,3): 170-reg budget -> full tr16 hoist fits (no spill).
__global__ __launch_bounds__(256, 3)
void attn_kernel(const u16* __restrict__ QKV, u16* __restrict__ Opart,
                 float* __restrict__ ml, u16* __restrict__ O)
{
  __shared__ u16 Ks[2][64*64];      // 8KB each, swizzled: LDS(r,cb)=K(r, cb^((r&7)<<4))
  __shared__ u16 Vp[2][4*1024];     // 8KB each, 4 panels [64 kv][16 d]
  int tid = threadIdx.x, wid = tid>>6, lane = tid&63;
  int l15 = lane&15, q5 = lane&31, hi = lane>>5;
  int bid = blockIdx.x;
  int qt, kt0, kt1, cid = bid;
  bool split = (bid < 768);
  if (split){
    int idx = bid >> 4;              // 0..47 heavy-first
    qt = 31 - (idx >> 1);            // 31..8
    int half = idx & 1;
    int nk = 2*qt + 2, h0 = nk >> 1; // qt+1
    kt0 = half ? h0 : 0; kt1 = half ? nk : h0;
  } else {
    qt = 7 - ((bid - 768) >> 4);
    kt0 = 0; kt1 = 2*qt + 2;
  }
  int bh = bid & 15;
  int b = bh>>3, h = bh&7;
  size_t qkvb = (size_t)b*1536 + h*64;
  size_t vbh  = (size_t)b*512  + h*64;

  int qrow = qt*128 + wid*32 + q5;        // this lane's q (column of S^T/O^T)
  short8 aQ[4];
#pragma unroll
  for (int kc=0; kc<4; ++kc)
    aQ[kc] = *(const short8*)(QKV + (size_t)qrow*3072 + qkvb + 16*kc + 8*hi);

  f32x16 oacc[2];
#pragma unroll
  for (int dblk=0; dblk<2; ++dblk)
#pragma unroll
    for (int r=0;r<16;r++) oacc[dblk][r] = 0.f;
  float mrun = -3e38f, lrun = 0.f;

#define STAGE(KT, BUF)                                                              \
  {                                                                                 \
    _Pragma("unroll")                                                               \
    for (int i=0;i<2;++i){                                                          \
      gload_lds16(QKV + (size_t)((KT)*64 + wid*16 + i*8 + (lane>>3))*3072 + qkvb    \
                      + 512 + (((lane&7)^(lane>>3))<<3),                            \
                  &Ks[BUF][(wid*16 + i*8)*64]);                                     \
      int j = wid*2 + i, p = j>>1, rh = (j&1)*32;                                   \
      gload_lds16(QKV + (size_t)((KT)*64 + rh + (lane>>1))*3072 + qkvb              \
                      + 1024 + p*16 + ((lane&1)<<3),                                \
                  &Vp[BUF][p*1024 + rh*16]);                                        \
    }                                                                               \
  }

  STAGE(kt0, 0);
  int cur = 0;

  for (int kt=kt0; kt<kt1; ++kt){
    __syncthreads();                 // drains DMA -> buf[cur] ready
    if (kt+1 < kt1) STAGE(kt+1, cur^1);

    // S^T = K @ Q^T : col=q5, 2 sub-accs of 32 kv rows
    f32x16 sacc[2];
#pragma unroll
    for (int s=0;s<2;s++)
#pragma unroll
      for (int r=0;r<16;r++) sacc[s][r] = 0.f;
    __builtin_amdgcn_s_setprio(1);
#pragma unroll
    for (int kc=0; kc<4; ++kc)
#pragma unroll
      for (int s=0; s<2; ++s){
        int cb = (32*kc + 16*hi) ^ ((q5&7)<<4);   // bytes, XOR read swizzle
        short8 aK = *(const short8*)&Ks[cur][(32*s + q5)*64 + (cb>>1)];
        sacc[s] = MFMA32(aK, aQ[kc], sacc[s]);
      }
    __builtin_amdgcn_s_setprio(0);

    // issue ALL V transpose-reads now; LDS latency hides under softmax (32 VGPR)
    uint2 av[4][2][2];
#pragma unroll
    for (int kc=0; kc<4; ++kc)
#pragma unroll
      for (int dblk=0; dblk<2; ++dblk){
        const u16* base = &Vp[cur][(((lane>>4)&1) + 2*dblk)*1024 + (16*kc + 8*hi)*16 + l15*4];
        av[kc][dblk][0] = tr16<0>(base);
        av[kc][dblk][1] = tr16<128>(base);
      }

    // lane-local online softmax (values pre-scaled into exp2 domain)
    bool diag = (kt >= 2*qt);
    float pm[4] = {-3e38f,-3e38f,-3e38f,-3e38f};
#pragma unroll
    for (int s=0;s<2;++s)
#pragma unroll
      for (int r=0;r<16;++r){
        float x = sacc[s][r];
        if (diag){
          int kv = kt*64 + 32*s + (r&3) + 8*(r>>2) + 4*hi;
          if (kv > qrow) x = -3e38f;
          sacc[s][r] = x;
        }
        pm[r&3] = fmaxf(pm[r&3], x);
      }
    float pmax = fmaxf(fmaxf(pm[0],pm[1]), fmaxf(pm[2],pm[3]));
    pmax = cross_max(pmax);
    // T13 defer-max: only rescale when max grew by > 8 (P bounded by 2^8)
    if (!__all(pmax <= mrun + 8.f)){
      float mn = fmaxf(mrun, pmax);
      float alpha = EXP2F(mrun - mn);
      mrun = mn;
      lrun *= alpha;
#pragma unroll
      for (int dblk=0; dblk<2; ++dblk)
#pragma unroll
        for (int r=0;r<16;++r) oacc[dblk][r] *= alpha;
    }
    float ps = 0.f;
    u32 Wp[2][4][2];
#pragma unroll
    for (int s=0;s<2;++s)
#pragma unroll
      for (int p=0;p<4;++p){
        float e0 = EXP2F(sacc[s][4*p+0]-mrun);
        float e1 = EXP2F(sacc[s][4*p+1]-mrun);
        float e2 = EXP2F(sacc[s][4*p+2]-mrun);
        float e3 = EXP2F(sacc[s][4*p+3]-mrun);
        ps += (e0+e1)+(e2+e3);
        Wp[s][p][0] = cvtpk(e0,e1);
        Wp[s][p][1] = cvtpk(e2,e3);
      }
    ps = cross_sum(ps);
    lrun += ps;

    // single wait for all tr-reads (issued pre-softmax), then pure-reg PV
    asm volatile("s_waitcnt lgkmcnt(0)");
    __builtin_amdgcn_sched_barrier(0);
    __builtin_amdgcn_s_setprio(1);
#pragma unroll
    for (int kc=0; kc<4; ++kc){
      int s = kc>>1, pA = (2*kc)&3, pB = (2*kc+1)&3;
      auto r0 = __builtin_amdgcn_permlane32_swap(Wp[s][pA][0], Wp[s][pB][0], false, false);
      auto r1 = __builtin_amdgcn_permlane32_swap(Wp[s][pA][1], Wp[s][pB][1], false, false);
      union { u32 w[4]; short8 s8; } bp;
      bp.w[0]=r0[0]; bp.w[1]=r1[0]; bp.w[2]=r0[1]; bp.w[3]=r1[1];
      union { uint2 u2[2]; short8 s8; } a0, a1;
      a0.u2[0]=av[kc][0][0]; a0.u2[1]=av[kc][0][1];
      a1.u2[0]=av[kc][1][0]; a1.u2[1]=av[kc][1][1];
      oacc[0] = MFMA32(a0.s8, bp.s8, oacc[0]);
      oacc[1] = MFMA32(a1.s8, bp.s8, oacc[1]);
    }
    __builtin_amdgcn_s_setprio(0);
    cur ^= 1;
  }

  if (split){
    // unnormalized partial O^T + (m,l) per q
    u16* po = Opart + (size_t)cid*8192 + (wid*32 + q5)*64;
#pragma unroll
    for (int dblk=0; dblk<2; ++dblk)
#pragma unroll
      for (int p=0;p<4;++p){
        int d0 = 32*dblk + 8*p + 4*hi;
        union { uint2 u; u16 hh[4]; } o;
#pragma unroll
        for (int r=0;r<4;++r) o.hh[r] = f2bf(oacc[dblk][4*p+r]);
        *(uint2*)(po + d0) = o.u;
      }
    if (lane < 32){
      ml[((size_t)cid*128 + wid*32 + q5)*2 + 0] = mrun;
      ml[((size_t)cid*128 + wid*32 + q5)*2 + 1] = lrun;
    }
  } else {
    float rcp = 1.f / lrun;
#pragma unroll
    for (int dblk=0; dblk<2; ++dblk)
#pragma unroll
      for (int p=0;p<4;++p){
        int d0 = 32*dblk + 8*p + 4*hi;
        union { uint2 u; u16 hh[4]; } o;
#pragma unroll
        for (int r=0;r<4;++r) o.hh[r] = f2bf(oacc[dblk][4*p+r] * rcp);
        *(uint2*)(O + (size_t)qrow*1024 + vbh + d0) = o.u;
      }
  }
#undef STAGE
}

// ---------------- combine: merge 2 kv-chunks for qt>=8 -----------------------
__global__ __launch_bounds__(128)
void attn_combine(const u16* __restrict__ Opart, const float* __restrict__ ml,
                  u16* __restrict__ O)
{
  int cb = blockIdx.x >> 4;                  // 0..23
  int qt = 31 - cb;                          // 31..8
  int bh = blockIdx.x & 15;
  int b = bh>>3, h = bh&7;
  int q = threadIdx.x;                       // 0..127
  int cid0 = (cb*2)*16 + bh, cid1 = cid0 + 16;
  float m0 = ml[((size_t)cid0*128 + q)*2], l0 = ml[((size_t)cid0*128 + q)*2 + 1];
  float m1 = ml[((size_t)cid1*128 + q)*2], l1 = ml[((size_t)cid1*128 + q)*2 + 1];
  float mx = fmaxf(m0, m1);
  float w0 = EXP2F(m0 - mx), w1 = EXP2F(m1 - mx);
  float rcp = 1.f / (w0*l0 + w1*l1);
  w0 *= rcp; w1 *= rcp;
  const u16* p0 = Opart + ((size_t)cid0*128 + q)*64;
  const u16* p1 = Opart + ((size_t)cid1*128 + q)*64;
  u16* o = O + (size_t)(qt*128 + q)*1024 + b*512 + h*64;
#pragma unroll
  for (int d0=0; d0<64; d0+=8){
    union { uint4 v; u16 s[8]; } a, c, r;
    a.v = *(const uint4*)(p0 + d0);
    c.v = *(const uint4*)(p1 + d0);
#pragma unroll
    for (int j=0;j<8;j++) r.s[j] = f2bf(w0*bf2f(a.s[j]) + w1*bf2f(c.s[j]));
    *(uint4*)(o + d0) = r.v;
  }
}

// ---------------- launch ----------------
extern "C" void kernel_launch(void* const* d_in, const int* in_sizes, int n_in,
                              void* d_out, int out_size, void* d_ws, size_t ws_size,
                              hipStream_t stream)
{
  float* out = (float*)d_out;
  const float* src_f = (const float*)d_in[0];
  char* ws = (char*)d_ws;
  const size_t MB = 1024ull*1024ull;
  u16* xbuf = (u16*)(ws);            // [0,8)   x ; later attn-out
  u16* xr   = (u16*)(ws +  8*MB);    // [8,16)  RoPE(x) ; later src2
  u16* qkv  = (u16*)(ws + 16*MB);    // [16,40) fused Q|K|V [8192][1536]
  u16* y2   = (u16*)(ws + 16*MB);    // [16,24) LN2 out (qkv dead by then)
  u16* hb   = (u16*)(ws + 24*MB);    // [24,56) FFN hidden
  u16* opart= (u16*)(ws + 40*MB);    // [40,52) attn partials (dead before FFN1)
  float* mlb= (float*)(ws + 52*MB);  // [52,52.75) m/l partials
  u16* arena= (u16*)(ws + 56*MB);    // ~7.33MB converted bf16 weights
  u16* attn = xbuf;
  u16* src2 = xr;

  ConvArgs ca;
  u16* cv[15]; cv[0] = nullptr;
  {
    size_t off = 0; int blk = 0;
    for (int i=1;i<15;i++){
      cv[i] = arena + off;
      int n = in_sizes[i];
      ca.in[i-1]  = (const float4*)d_in[i];
      ca.out[i-1] = (uint2*)cv[i];
      ca.n4[i-1]  = n >> 2;
      ca.sb[i-1]  = blk;
      blk += ((n>>2) + 255) / 256;
      off += (size_t)n;
    }
    ca.sb[14] = blk;
    conv_all<<<blk, 256, 0, stream>>>(ca);
  }
  const u16* rcos = cv[1];
  const u16* rsin = cv[2];
  const u16* inw  = cv[3];
  const u16* inb  = cv[4];
  const u16* outw = cv[5];
  const u16* outb = cv[6];
  const u16* w1   = cv[7];
  const u16* b1   = cv[8];
  const u16* w2   = cv[9];
  const u16* b2   = cv[10];
  const u16* ln1w = cv[11];
  const u16* ln1b = cv[12];
  const u16* ln2w = cv[13];
  const u16* ln2b = cv[14];

  ln_kernel<1,1><<<2048, 256, 0, stream>>>(src_f, ln1w, ln1b, rcos, rsin, xbuf, xr);

  // fused Q|K|V projection: A = xr for cols<1024 (bn<8), xbuf for V cols (bn>=8)
  gemm_bt<EPI_NONE,0,0,1,1,64><<<1536, 256, 0, stream>>>(xr, inw, inb, xbuf, qkv, 8192, 1536, 512);

  attn_kernel<<<896, 256, 0, stream>>>(qkv, opart, mlb, attn);
  attn_combine<<<384, 128, 0, stream>>>(opart, mlb, attn);

  gemm_bt<EPI_RES,1,0,0,0,64><<<512, 256, 0, stream>>>(attn, outw, outb, src_f, src2, 8192, 512, 512);

  ln_kernel<0,0><<<2048, 256, 0, stream>>>(src2, ln2w, ln2b, nullptr, nullptr, y2, nullptr);

  gemm_bt<EPI_GELU,0,0,0,0,64><<<2048, 256, 0, stream>>>(y2, w1, b1, nullptr, hb, 8192, 2048, 512);
  gemm_bt<EPI_RES,0,1,0,0,64><<<512, 256, 0, stream>>>(hb, w2, b2, src2, out, 8192, 512, 2048);
}